// Round 3
// baseline (1979.642 us; speedup 1.0000x reference)
//
#include <hip/hip_runtime.h>

// ---------- types / helpers ----------
typedef __attribute__((ext_vector_type(8))) _Float16 f16x8;
typedef __attribute__((ext_vector_type(4))) float floatx4;

union HFrag { uint4 u4; f16x8 v; unsigned short s[8]; };
union HS { _Float16 h; unsigned short u; };

__device__ __forceinline__ float bf2f(unsigned short u) {
  return __uint_as_float(((unsigned int)u) << 16);
}
__device__ __forceinline__ float h2f(unsigned short u) { HS z; z.u = u; return (float)z.h; }
__device__ __forceinline__ unsigned short f2h(float f) { HS z; z.h = (_Float16)f; return z.u; }
__device__ __forceinline__ float sigmf(float x) { return 1.0f / (1.0f + expf(-x)); }

// dtype-agnostic input load: f32 ? float : bf16
__device__ __forceinline__ float ldi(const void* p, long i, bool f32) {
  return f32 ? ((const float*)p)[i] : bf2f(((const unsigned short*)p)[i]);
}

// async global->LDS DMA, 16B per lane. LDS dest = wave-uniform base + lane*16.
__device__ __forceinline__ void dma16(unsigned short* lds, const unsigned short* g) {
  __builtin_amdgcn_global_load_lds(
      (const __attribute__((address_space(1))) unsigned int*)g,
      (__attribute__((address_space(3))) unsigned int*)lds,
      16, 0, 0);
}

// wave-local waits (gfx9 encoding: vm [3:0]|[15:14], exp [6:4], lgkm [11:8])
#define WAIT_VM8()   __builtin_amdgcn_s_waitcnt(0x0F78)
#define WAIT_VM4()   __builtin_amdgcn_s_waitcnt(0x0F74)
#define WAIT_VM0()   __builtin_amdgcn_s_waitcnt(0x0F70)
#define WAIT_LGKM0() __builtin_amdgcn_s_waitcnt(0xC07F)

// barrier that does NOT drain vmcnt (keeps Bt DMA pipeline alive across it);
// sched_barrier pins ordering so LDS ops can't be hoisted/sunk across.
#define SAFE_BARRIER() do {                      \
  __builtin_amdgcn_sched_barrier(0);             \
  WAIT_LGKM0();                                  \
  __builtin_amdgcn_s_barrier();                  \
  __builtin_amdgcn_sched_barrier(0);             \
} while (0)

#define NNODES 32000
#define NEDGES 80000
#define NGRAPH 1000

#define MFMA_F16 __builtin_amdgcn_mfma_f32_16x16x32_f16

// ---------- dtype detect ----------
__global__ __launch_bounds__(256) void detect_kernel(
    const unsigned short* __restrict__ nf, int* __restrict__ flag) {
  __shared__ float sm[256];
  float m = 0.f;
  for (int i = threadIdx.x; i < 4096; i += 256) {
    float v = fabsf(bf2f(nf[i]));
    if (isfinite(v)) m = fmaxf(m, v);
    else m = 1e30f;
  }
  sm[threadIdx.x] = m;
  __syncthreads();
  if (threadIdx.x == 0) {
    float mm = 0.f;
    for (int i = 0; i < 256; ++i) mm = fmaxf(mm, sm[i]);
    flag[0] = (mm > 1e6f) ? 1 : 0;
  }
}

// ---------- prep: GRU weights -> fp16 [192][64] (j-major, transposed) ----------
__global__ __launch_bounds__(256) void prep_kernel(
    const int* __restrict__ dflag,
    const void* __restrict__ Wx, const void* __restrict__ Wh,
    const void* __restrict__ bx, const void* __restrict__ bh,
    const void* __restrict__ bconv,
    unsigned short* __restrict__ WxH, unsigned short* __restrict__ WhH,
    float* __restrict__ bxf, float* __restrict__ bhf, float* __restrict__ bconvf) {
  bool f32 = dflag[0] != 0;
  int idx = blockIdx.x * 256 + threadIdx.x;   // grid 48 -> 12288 = 192*64
  int j = idx >> 6, k = idx & 63;
  WxH[idx] = f2h(ldi(Wx, k * 192 + j, f32));
  WhH[idx] = f2h(ldi(Wh, k * 192 + j, f32));
  if (idx < 192) { bxf[idx] = ldi(bx, idx, f32); bhf[idx] = ldi(bh, idx, f32); }
  if (idx < 64) bconvf[idx] = ldi(bconv, idx, f32);
}

// ---------- prep: LSTM weights -> chunk-major float4 [chunk][gate] ----------
__global__ __launch_bounds__(256) void lstmprep_kernel(
    const int* __restrict__ dflag,
    const void* Wx0, const void* Wh0, const void* bx0, const void* bh0,
    const void* Wx1, const void* Wh1, const void* bx1, const void* bh1,
    const void* Wx2, const void* Wh2, const void* bx2, const void* bh2,
    float4* __restrict__ LW, float* __restrict__ bsum) {
  bool f32 = dflag[0] != 0;
  int idx = blockIdx.x * 256 + threadIdx.x;   // grid 112 -> 28672 float4
  int l, base, fi;
  if (idx < 12288)      { l = 0; base = 0;     fi = 128; }
  else if (idx < 20480) { l = 1; base = 12288; fi = 64; }
  else                  { l = 2; base = 20480; fi = 64; }
  const void* Wx = (l == 0) ? Wx0 : (l == 1) ? Wx1 : Wx2;
  const void* Wh = (l == 0) ? Wh0 : (l == 1) ? Wh1 : Wh2;
  int r = idx - base;
  int c = r >> 8, t = r & 255;
  float v[4];
#pragma unroll
  for (int i2 = 0; i2 < 4; ++i2) {
    int k = c * 4 + i2;
    v[i2] = (k < fi) ? ldi(Wx, (long)k * 256 + t, f32)
                     : ldi(Wh, (long)(k - fi) * 256 + t, f32);
  }
  float4 o; o.x = v[0]; o.y = v[1]; o.z = v[2]; o.w = v[3];
  LW[idx] = o;
  if (idx < 768) {
    int ll = idx >> 8, j = idx & 255;
    const void* bx = (ll == 0) ? bx0 : (ll == 1) ? bx1 : bx2;
    const void* bh = (ll == 0) ? bh0 : (ll == 1) ? bh1 : bh2;
    bsum[idx] = ldi(bx, j, f32) + ldi(bh, j, f32);
  }
}

// ---------- node projection: h = relu(nf @ Wp + bp) ----------
__global__ __launch_bounds__(256) void nodeproj_kernel(
    const int* __restrict__ dflag,
    const void* __restrict__ nf, const void* __restrict__ Wp,
    const void* __restrict__ bp, float* __restrict__ hstate) {
  bool f32 = dflag[0] != 0;
  int lane = threadIdx.x & 63;
  int n = blockIdx.x * 4 + (threadIdx.x >> 6);
  float acc = ldi(bp, lane, f32);
  for (int k = 0; k < 74; ++k)
    acc += ldi(nf, (long)n * 74 + k, f32) * ldi(Wp, k * 64 + lane, f32);
  hstate[n * 64 + lane] = fmaxf(acc, 0.0f);
}

// ---------- We2T: fp16 B^T tiles for Z-GEMM ----------
// layout: [kc 64][row 128][g' 8][j 8], row = klocal*64 + o, d = g*8+j,
// stored granule g' = g ^ (row&7)  (bank-conflict-free b128 frag reads)
// value = We2[k][d*64 + o], k = kc*2 + klocal
__global__ __launch_bounds__(256) void we2t_kernel(
    const int* __restrict__ dflag,
    const void* __restrict__ We2, unsigned short* __restrict__ We2T) {
  bool f32 = dflag[0] != 0;
  int idx = blockIdx.x * 256 + threadIdx.x;  // grid 2048 -> 524288
  int j = idx & 7;
  int gs = (idx >> 3) & 7;
  int row = (idx >> 6) & 127;
  int kc = idx >> 13;
  int g = gs ^ (row & 7);
  int d = g * 8 + j;
  int o = row & 63;
  int k = kc * 2 + (row >> 6);
  We2T[idx] = f2h(ldi(We2, (long)k * 4096 + d * 64 + o, f32));
}

// ---------- be2T: fp16 B^T for hbe GEMM: [o 64][g' 8][j 8], g' = g^(o&7) ----
__global__ __launch_bounds__(256) void be2t_kernel(
    const int* __restrict__ dflag,
    const void* __restrict__ be2, unsigned short* __restrict__ be2T) {
  bool f32 = dflag[0] != 0;
  int idx = blockIdx.x * 256 + threadIdx.x;  // grid 16 -> 4096
  int j = idx & 7;
  int gs = (idx >> 3) & 7;
  int o = idx >> 6;
  int g = gs ^ (o & 7);
  int d = g * 8 + j;
  be2T[idx] = f2h(ldi(be2, (long)d * 64 + o, f32));
}

// ---------- CSR build (once per launch; dst is launch-invariant) ----------
__global__ __launch_bounds__(256) void count_kernel(
    const int* __restrict__ dst, int* __restrict__ cnt) {
  int e = blockIdx.x * 256 + threadIdx.x;
  if (e < NEDGES) atomicAdd(&cnt[dst[e]], 1);
}

__global__ __launch_bounds__(256) void scan_kernel(
    const int* __restrict__ cnt, int* __restrict__ row_ptr, int* __restrict__ cur) {
  __shared__ int part[256];
  int t = threadIdx.x;
  int base = t * 125;              // 256*125 = 32000
  int s = 0;
  for (int i = 0; i < 125; ++i) s += cnt[base + i];
  part[t] = s;
  __syncthreads();
  if (t == 0) {
    int run = 0;
    for (int i = 0; i < 256; ++i) { int v = part[i]; part[i] = run; run += v; }
  }
  __syncthreads();
  int run = part[t];
  for (int i = 0; i < 125; ++i) {
    row_ptr[base + i] = run;
    cur[base + i] = run;
    run += cnt[base + i];
  }
  if (t == 255) row_ptr[32000] = run;
}

__global__ __launch_bounds__(256) void fill_kernel(
    const int* __restrict__ dst, int* __restrict__ cur, int* __restrict__ eidx) {
  int e = blockIdx.x * 256 + threadIdx.x;
  if (e < NEDGES) { int p = atomicAdd(&cur[dst[e]], 1); eidx[p] = e; }
}

// ---------- message passing, nodes-first (Z) formulation ----------
// Block = 64 nodes (2 graphs) + ALL their in-edges (src is in-block by
// construction: edges stay within graphs).
//   Z[n][k][o] = sum_d h[n][d] * We2[k][d*64+o]   (k-chunked, 2 k per chunk)
//   msg[e][o]  = sum_k u[e][k] * Z[src[e]][k][o] + (h@be2)[src[e]][o]
// EH=128 -> 64 k-chunks of 2. We2 stream: 1 MB per 64-NODE block (500 blocks
// = 500 MB/step) vs the old 64-EDGE blocks (1250 = 1.25 GB/step). h enters
// MFMA as hi/lo fp16 (f32-equivalent); u recomputed per chunk in f32.
__global__ __launch_bounds__(256) void msg_z_kernel(
    const int* __restrict__ dflag,
    const float* __restrict__ hstate,
    const void* __restrict__ ef, const void* __restrict__ We1,
    const void* __restrict__ be1,
    const unsigned short* __restrict__ We2T,
    const unsigned short* __restrict__ be2T,
    const int* __restrict__ src, const int* __restrict__ eidx,
    const int* __restrict__ row_ptr,
    float* __restrict__ msgbuf) {
  bool f32 = dflag[0] != 0;
  __shared__ __align__(16) unsigned short hhi[64][72];    //  9216 B
  __shared__ __align__(16) unsigned short hlo[64][72];    //  9216 B
  __shared__ __align__(16) unsigned short BtL[2][8192];   // 32768 B (dbuf)
  __shared__ __align__(16) float Zs[8192];                // 32768 B [64][128] swz
  __shared__ __align__(16) unsigned short beT[4096];      //  8192 B
  __shared__ float we1_s[1536];                           //  6144 B
  __shared__ float be1_s[128];                            //   512 B
  // total ~98.8 KB -> 1 block/CU

  int t = threadIdx.x, lane = t & 63, w = t >> 6;
  int c = lane & 15, q = lane >> 4;
  int nb = blockIdx.x * 64;                               // 500 blocks
  int p0 = row_ptr[nb], p1 = row_ptr[nb + 64];
  int nE = p1 - p0;
  if (nE <= 0) return;

  // ---- stage h (hi/lo fp16), We1, be1; DMA be2T (wave-private rows) ----
  for (int i = t; i < 4096; i += 256) {
    int n = i >> 6, cc = i & 63;
    float v = hstate[(size_t)(nb + n) * 64 + cc];
    HS hi; hi.h = (_Float16)v;
    hhi[n][cc] = hi.u;
    hlo[n][cc] = f2h(v - (float)hi.h);
  }
  for (int i = t; i < 1536; i += 256) we1_s[i] = ldi(We1, i, f32);
  if (t < 128) be1_s[t] = ldi(be1, t, f32);
  dma16(beT + w * 1024, be2T + w * 1024 + lane * 8);
  dma16(beT + w * 1024 + 512, be2T + w * 1024 + 512 + lane * 8);
  SAFE_BARRIER();                       // h/We1 visible; beT DMA still in flight

  // ---- edge tiles of 256 (virtually always a single tile) ----
  for (int et = 0; et < nE; et += 256) {
    int me = et + t;
    bool act = me < nE;
    int pos = p0 + (act ? me : 0);
    int eg = eidx[pos];
    int r = src[eg] - nb;               // 0..63 (in-graph edges)
    float efr[12];
#pragma unroll
    for (int j = 0; j < 12; ++j) efr[j] = ldi(ef, (long)eg * 12 + j, f32);

    // ---- prefetch Bt chunks 0,1 (wave-private quarters: rows it will read) --
#pragma unroll
    for (int b = 0; b < 2; ++b) {
      unsigned short* L = &BtL[b][0];
      const unsigned short* G = We2T + b * 8192;
      int o1 = w * 1024, o2 = 4096 + w * 1024;
      dma16(L + o1, G + o1 + lane * 8);
      dma16(L + o1 + 512, G + o1 + 512 + lane * 8);
      dma16(L + o2, G + o2 + lane * 8);
      dma16(L + o2 + 512, G + o2 + 512 + lane * 8);
    }
    WAIT_VM8();                         // beT ready (oldest 2 drained)

    // ---- hbe = (h_hi + h_lo) @ be2  -> Zs cols 0..63 (swizzled) ----
    floatx4 hacc[4];
#pragma unroll
    for (int mt = 0; mt < 4; ++mt) hacc[mt] = (floatx4){0.f, 0.f, 0.f, 0.f};
#pragma unroll
    for (int ks = 0; ks < 2; ++ks) {
      HFrag bb;
      bb.u4 = *(const uint4*)&beT[(w * 16 + c) * 64 + (((ks * 4 + q) ^ (c & 7)) * 8)];
#pragma unroll
      for (int mt = 0; mt < 4; ++mt) {
        HFrag ah, al;
        ah.u4 = *(const uint4*)&hhi[mt * 16 + c][ks * 32 + q * 8];
        al.u4 = *(const uint4*)&hlo[mt * 16 + c][ks * 32 + q * 8];
        hacc[mt] = MFMA_F16(ah.v, bb.v, hacc[mt], 0, 0, 0);
        hacc[mt] = MFMA_F16(al.v, bb.v, hacc[mt], 0, 0, 0);
      }
    }
    SAFE_BARRIER();                     // prev tile's Zs readers done
#pragma unroll
    for (int mt = 0; mt < 4; ++mt) {
#pragma unroll
      for (int reg = 0; reg < 4; ++reg) {
        int row = mt * 16 + q * 4 + reg;
        int col = w * 16 + c;
        int gp = (col >> 2) ^ (row & 15);
        Zs[row * 128 + gp * 4 + (col & 3)] = hacc[mt][reg];
      }
    }
    SAFE_BARRIER();                     // hbe visible

    // ---- msg init from hbe ----
    floatx4 msgv[16];
    int rb = r * 128, rx = r & 15;
    if (act) {
#pragma unroll
      for (int og = 0; og < 16; ++og)
        msgv[og] = *(const floatx4*)&Zs[rb + (og ^ rx) * 4];
    }

    // ---- k-chunk loop: 64 chunks x 2 k  (EH = 128) ----
    for (int kc = 0; kc < 64; ++kc) {
      if (kc == 63) WAIT_VM0(); else WAIT_VM4();   // Bt(kc) complete
      // B-frags (wave reads only rows its own DMA wrote)
      HFrag bf[2][2];
#pragma unroll
      for (int nt2 = 0; nt2 < 2; ++nt2)
#pragma unroll
        for (int ks = 0; ks < 2; ++ks) {
          int row = (nt2 * 4 + w) * 16 + c;
          int gq = (ks * 4 + q) ^ (c & 7);
          bf[nt2][ks].u4 = *(const uint4*)&BtL[kc & 1][row * 64 + gq * 8];
        }
      __builtin_amdgcn_sched_barrier(0);
      WAIT_LGKM0();                     // B-frags in regs before buffer reuse
      __builtin_amdgcn_sched_barrier(0);
      if (kc + 2 < 64) {                // prefetch Bt(kc+2) into freed buffer
        unsigned short* L = &BtL[kc & 1][0];
        const unsigned short* G = We2T + (kc + 2) * 8192;
        int o1 = w * 1024, o2 = 4096 + w * 1024;
        dma16(L + o1, G + o1 + lane * 8);
        dma16(L + o1 + 512, G + o1 + 512 + lane * 8);
        dma16(L + o2, G + o2 + lane * 8);
        dma16(L + o2 + 512, G + o2 + 512 + lane * 8);
      }
      // Z-GEMM: zacc = (h_hi + h_lo) @ Bt(kc)
      floatx4 zacc[4][2];
#pragma unroll
      for (int mt = 0; mt < 4; ++mt)
#pragma unroll
        for (int nt2 = 0; nt2 < 2; ++nt2)
          zacc[mt][nt2] = (floatx4){0.f, 0.f, 0.f, 0.f};
#pragma unroll
      for (int ks = 0; ks < 2; ++ks) {
#pragma unroll
        for (int mt = 0; mt < 4; ++mt) {
          HFrag ah, al;
          ah.u4 = *(const uint4*)&hhi[mt * 16 + c][ks * 32 + q * 8];
          al.u4 = *(const uint4*)&hlo[mt * 16 + c][ks * 32 + q * 8];
#pragma unroll
          for (int nt2 = 0; nt2 < 2; ++nt2) {
            zacc[mt][nt2] = MFMA_F16(ah.v, bf[nt2][ks].v, zacc[mt][nt2], 0, 0, 0);
            zacc[mt][nt2] = MFMA_F16(al.v, bf[nt2][ks].v, zacc[mt][nt2], 0, 0, 0);
          }
        }
      }
      SAFE_BARRIER();                   // all Zs readers of prev chunk done
#pragma unroll
      for (int mt = 0; mt < 4; ++mt)
#pragma unroll
        for (int nt2 = 0; nt2 < 2; ++nt2) {
          int ntile = nt2 * 4 + w;
#pragma unroll
          for (int reg = 0; reg < 4; ++reg) {
            int row = mt * 16 + q * 4 + reg;
            int col = ntile * 16 + c;
            int gp = (col >> 2) ^ (row & 15);
            Zs[row * 128 + gp * 4 + (col & 3)] = zacc[mt][nt2][reg];
          }
        }
      SAFE_BARRIER();                   // Z(kc) visible

      // edge pass: u (f32, recomputed) x Z rows
      if (act) {
        int k0 = kc * 2;
        float u0 = be1_s[k0], u1 = be1_s[k0 + 1];
#pragma unroll
        for (int j = 0; j < 12; ++j) {
          u0 += efr[j] * we1_s[j * 128 + k0];
          u1 += efr[j] * we1_s[j * 128 + k0 + 1];
        }
        u0 = fmaxf(u0, 0.f); u1 = fmaxf(u1, 0.f);
#pragma unroll
        for (int og = 0; og < 16; ++og) {
          floatx4 z0 = *(const floatx4*)&Zs[rb + (og ^ rx) * 4];
          floatx4 z1 = *(const floatx4*)&Zs[rb + (16 + (og ^ rx)) * 4];
          msgv[og] += u0 * z0 + u1 * z1;
        }
      }
    }

    // ---- store msg (CSR position order, same contract as before) ----
    if (act) {
      float* mp = msgbuf + (size_t)pos * 64;
#pragma unroll
      for (int og = 0; og < 16; ++og) *(floatx4*)(mp + og * 4) = msgv[og];
    }
  }
}

// ---------- GRU step: MFMA gates (fp16, X hi/lo split) + fused CSR gather ------
__global__ __launch_bounds__(256, 2) void gru_kernel(
    float* __restrict__ hstate, const float* __restrict__ msgbuf,
    const int* __restrict__ row_ptr,
    const unsigned short* __restrict__ WxH, const unsigned short* __restrict__ WhH,
    const float* __restrict__ bxf, const float* __restrict__ bhf,
    const float* __restrict__ bconvf) {
  __shared__ __align__(16) unsigned short Xhi[64][72];   // 9216 B
  __shared__ __align__(16) unsigned short Xlo[64][72];   // 9216 B
  __shared__ __align__(16) unsigned short Hh[64][72];    // 9216 B
  __shared__ unsigned short SRZ[128][68];                // 17408 B (fp16 sig(r/z))
  __shared__ float GXn[64][66];                          // 16896 B
  __shared__ float GHn[64][66];                          // 16896 B
  int t = threadIdx.x;
  int nb = blockIdx.x * 64;                              // 500 blocks

#pragma unroll
  for (int i = 0; i < 16; ++i) {
    int idx = t + i * 256;
    int n = idx >> 6, c = idx & 63;
    int node = nb + n;
    float a = bconvf[c];
    int p0 = row_ptr[node], p1 = row_ptr[node + 1];
    for (int p = p0; p < p1; ++p) a += msgbuf[(size_t)p * 64 + c];
    a = fmaxf(a, 0.f);
    HS hi; hi.h = (_Float16)a;
    Xhi[n][c] = hi.u;
    Xlo[n][c] = f2h(a - (float)hi.h);
    Hh[n][c] = f2h(hstate[(size_t)node * 64 + c]);
  }
  __syncthreads();

  int lane = t & 63, w = t >> 6;
  int c16 = lane & 15, q = lane >> 4;
  floatx4 gx[3][4], gh[3][4];
#pragma unroll
  for (int jt = 0; jt < 3; ++jt)
#pragma unroll
    for (int nt = 0; nt < 4; ++nt) {
      gx[jt][nt] = (floatx4){0.f, 0.f, 0.f, 0.f};
      gh[jt][nt] = (floatx4){0.f, 0.f, 0.f, 0.f};
    }
#pragma unroll
  for (int kc = 0; kc < 2; ++kc) {
    int kof = kc * 32 + q * 8;
    HFrag ax[3], ah[3];
#pragma unroll
    for (int jt = 0; jt < 3; ++jt) {
      long off = (long)((w * 3 + jt) * 16 + c16) * 64 + kof;
      ax[jt].u4 = *(const uint4*)(WxH + off);
      ah[jt].u4 = *(const uint4*)(WhH + off);
    }
    HFrag bxh[4], bxl[4], bhf_[4];
#pragma unroll
    for (int nt = 0; nt < 4; ++nt) {
      int n = nt * 16 + c16;
      bxh[nt].u4 = *(const uint4*)&Xhi[n][kof];
      bxl[nt].u4 = *(const uint4*)&Xlo[n][kof];
      bhf_[nt].u4 = *(const uint4*)&Hh[n][kof];
    }
#pragma unroll
    for (int jt = 0; jt < 3; ++jt)
#pragma unroll
      for (int nt = 0; nt < 4; ++nt) {
        gx[jt][nt] = MFMA_F16(ax[jt].v, bxh[nt].v, gx[jt][nt], 0, 0, 0);
        gx[jt][nt] = MFMA_F16(ax[jt].v, bxl[nt].v, gx[jt][nt], 0, 0, 0);
        gh[jt][nt] = MFMA_F16(ah[jt].v, bhf_[nt].v, gh[jt][nt], 0, 0, 0);
      }
  }

#pragma unroll
  for (int jt = 0; jt < 3; ++jt) {
#pragma unroll
    for (int rr = 0; rr < 4; ++rr) {
      int j = (w * 3 + jt) * 16 + q * 4 + rr;
      float bxv = bxf[j], bhv = bhf[j];
#pragma unroll
      for (int nt = 0; nt < 4; ++nt) {
        int n = nt * 16 + c16;
        float vx = gx[jt][nt][rr] + bxv;
        float vh = gh[jt][nt][rr] + bhv;
        if (j < 128) {
          SRZ[j][n] = f2h(sigmf(vx + vh));
        } else {
          GXn[j - 128][n] = vx;
          GHn[j - 128][n] = vh;
        }
      }
    }
  }
  __syncthreads();

#pragma unroll
  for (int i = 0; i < 16; ++i) {
    int idx = t + i * 256;
    int n = idx >> 6, f = idx & 63;
    float r = h2f(SRZ[f][n]);
    float z = h2f(SRZ[64 + f][n]);
    float ng = tanhf(GXn[f][n] + r * GHn[f][n]);
    size_t gi = (size_t)(nb + n) * 64 + f;
    float ho = hstate[gi];
    hstate[gi] = (1.0f - z) * ng + z * ho;
  }
}

// ---------- Set2Set fused x6 + head ----------
__global__ __launch_bounds__(512) void s2s6_kernel(
    const int* __restrict__ dflag,
    const float* __restrict__ hstate,
    const float4* __restrict__ LW,        // [l0:48|l1:32|l2:32] x 256 float4
    const float* __restrict__ lstm_bsum,  // [3][256] bx+bh
    const void* __restrict__ Wout1, const void* __restrict__ bout1,
    const void* __restrict__ Wout2, const void* __restrict__ bout2,
    float* __restrict__ out) {
  bool f32 = dflag[0] != 0;
  __shared__ float xq[4][128];        // q_star per graph
  __shared__ float inb[4][192];       // combined [xq(fi) | h(64)] per graph
  __shared__ float gates[4][256];
  __shared__ float al[4][32];
  __shared__ float hsvf[768];         // 3 layers x 4 graphs x 64
  __shared__ float csvf[768];
  int g0 = blockIdx.x * 4;
  int t = threadIdx.x;

  for (int i = t; i < 512; i += 512) xq[i >> 7][i & 127] = 0.f;
  for (int i = t; i < 768; i += 512) { hsvf[i] = 0.f; csvf[i] = 0.f; }
  __syncthreads();

  int tt = t & 255, gp = t >> 8;      // gate id, graph-pair
  int ga = gp * 2, gb = ga + 1;

  for (int s = 0; s < 6; ++s) {
#pragma unroll
    for (int l = 0; l < 3; ++l) {
      const int fi = (l == 0) ? 128 : 64;
      const int tot = fi + 64;
      for (int i = t; i < 4 * tot; i += 512) {
        int g = i / tot, k = i - g * tot;
        inb[g][k] = (k < fi) ? xq[g][k] : hsvf[l * 256 + g * 64 + (k - fi)];
      }
      __syncthreads();
      const int nch = tot >> 2;
      const float4* wrow = LW + ((l == 0) ? 0 : (l == 1) ? 12288 : 20480) + tt;
      float bs = lstm_bsum[l * 256 + tt];
      float a0 = bs, a1 = bs;
#pragma unroll 8
      for (int cch = 0; cch < nch; ++cch) {
        float4 wv = wrow[(size_t)cch * 256];
        float4 x0 = *(const float4*)&inb[ga][cch * 4];
        float4 x1 = *(const float4*)&inb[gb][cch * 4];
        a0 += wv.x * x0.x + wv.y * x0.y + wv.z * x0.z + wv.w * x0.w;
        a1 += wv.x * x1.x + wv.y * x1.y + wv.z * x1.z + wv.w * x1.w;
      }
      gates[ga][tt] = a0;
      gates[gb][tt] = a1;
      __syncthreads();
      if (t < 256) {
        int gg = t >> 6, u = t & 63;
        float ig = sigmf(gates[gg][u]);
        float fg = sigmf(gates[gg][64 + u]);
        float gv = tanhf(gates[gg][128 + u]);
        float og = sigmf(gates[gg][192 + u]);
        int ci = l * 256 + t;
        float cc = fg * csvf[ci] + ig * gv;
        float hn = og * tanhf(cc);
        csvf[ci] = cc;
        hsvf[ci] = hn;
        xq[gg][u] = hn;
      }
      __syncthreads();
    }
    if (t < 256) {
      int gg = t >> 6, tl = t & 63;
      int g = g0 + gg;
      int n = tl & 31, half = tl >> 5;
      const float* hrow = hstate + (size_t)(g * 32 + n) * 64 + half * 32;
      const float* qp = &xq[gg][half * 32];
      float p = 0.f;
#pragma unroll
      for (int k = 0; k < 32; ++k) p += hrow[k] * qp[k];
      p += __shfl_xor(p, 32, 64);
      if (half == 0) {
        float m = p;
#pragma unroll
        for (int s2 = 1; s2 < 32; s2 <<= 1) m = fmaxf(m, __shfl_xor(m, s2, 32));
        float e = expf(p - m);
        float sum = e;
#pragma unroll
        for (int s2 = 1; s2 < 32; s2 <<= 1) sum += __shfl_xor(sum, s2, 32);
        al[gg][n] = e / sum;
      }
      float acc = 0.f;
#pragma unroll 8
      for (int nn = 0; nn < 32; ++nn)
        acc += al[gg][nn] * hstate[(size_t)(g * 32 + nn) * 64 + tl];
      xq[gg][64 + tl] = acc;
    }
    __syncthreads();
  }

  if (t < 256) {
    int gg = t >> 6, tl = t & 63;
    int g = g0 + gg;
    float acc = ldi(bout1, tl, f32);
#pragma unroll 16
    for (int k = 0; k < 128; ++k) acc += xq[gg][k] * ldi(Wout1, k * 64 + tl, f32);
    acc = fmaxf(acc, 0.0f);
    float p = acc * ldi(Wout2, tl, f32);
#pragma unroll
    for (int m = 1; m < 64; m <<= 1) p += __shfl_xor(p, m, 64);
    if (tl == 0) out[g] = p + ldi(bout2, 0, f32);
    out[1000 + g * 128 + tl] = xq[gg][tl];
    out[1000 + g * 128 + 64 + tl] = xq[gg][64 + tl];
  }
}

// ---------- launch ----------
extern "C" void kernel_launch(void* const* d_in, const int* in_sizes, int n_in,
                              void* d_out, int out_size, void* d_ws, size_t ws_size,
                              hipStream_t stream) {
  (void)in_sizes; (void)n_in; (void)out_size; (void)ws_size;
  const void* node_feats = d_in[0];
  const void* edge_feats = d_in[1];
  const int* src = (const int*)d_in[2];
  const int* dst = (const int*)d_in[3];
  const void* Wp = d_in[5];
  const void* bp = d_in[6];
  const void* We1 = d_in[7];
  const void* be1 = d_in[8];
  const void* We2 = d_in[9];
  const void* be2 = d_in[10];
  const void* b_conv = d_in[11];
  const void* gWx = d_in[12];
  const void* gWh = d_in[13];
  const void* gbx = d_in[14];
  const void* gbh = d_in[15];
  const void* Wout1 = d_in[16];
  const void* bout1 = d_in[17];
  const void* Wout2 = d_in[18];
  const void* bout2 = d_in[19];

  // workspace layout (~31.9 MB; proven-mapped region >= 44.5 MB)
  int* dflag = (int*)d_ws;                                    // 64 ints reserved
  float* hstate = (float*)d_ws + 64;                          // 32000*64 f32
  float* msgbuf = hstate + NNODES * 64;                       // 80000*64 f32
  unsigned short* We2T = (unsigned short*)(msgbuf + (size_t)NEDGES * 64); // 524288 fp16
  unsigned short* WxH = We2T + 524288;                        // 12288 fp16
  unsigned short* WhH = WxH + 12288;                          // 12288 fp16
  float* bxf = (float*)(WhH + 12288);                         // 192
  float* bhf = bxf + 192;                                     // 192
  float* bconvf = bhf + 192;                                  // 64
  int* row_ptr = (int*)(bconvf + 64);                         // 32001
  int* cur = row_ptr + 32001;                                 // 32000
  int* cnt = cur + 32000;                                     // 32000
  int* eidx = cnt + 32000;                                    // 80000
  uintptr_t lwp = (uintptr_t)(eidx + 80000);
  lwp = (lwp + 15) & ~(uintptr_t)15;                          // 16B align
  float4* LWf = (float4*)lwp;                                 // 28672 float4 (448 KB)
  float* lstm_bsum = (float*)(LWf + 28672);                   // 768 f32
  unsigned short* be2T = (unsigned short*)(lstm_bsum + 768);  // 4096 fp16

  (void)hipMemsetAsync(cnt, 0, (size_t)NNODES * sizeof(int), stream);

  detect_kernel<<<1, 256, 0, stream>>>((const unsigned short*)node_feats, dflag);
  prep_kernel<<<48, 256, 0, stream>>>(dflag, gWx, gWh, gbx, gbh, b_conv,
                                      WxH, WhH, bxf, bhf, bconvf);
  nodeproj_kernel<<<NNODES / 4, 256, 0, stream>>>(dflag, node_feats, Wp, bp, hstate);
  we2t_kernel<<<2048, 256, 0, stream>>>(dflag, We2, We2T);
  be2t_kernel<<<16, 256, 0, stream>>>(dflag, be2, be2T);
  lstmprep_kernel<<<112, 256, 0, stream>>>(dflag,
      d_in[20], d_in[21], d_in[22], d_in[23],
      d_in[24], d_in[25], d_in[26], d_in[27],
      d_in[28], d_in[29], d_in[30], d_in[31],
      LWf, lstm_bsum);

  count_kernel<<<(NEDGES + 255) / 256, 256, 0, stream>>>(dst, cnt);
  scan_kernel<<<1, 256, 0, stream>>>(cnt, row_ptr, cur);
  fill_kernel<<<(NEDGES + 255) / 256, 256, 0, stream>>>(dst, cur, eidx);

  for (int step = 0; step < 6; ++step) {
    msg_z_kernel<<<NNODES / 64, 256, 0, stream>>>(
        dflag, hstate, edge_feats, We1, be1, We2T, be2T, src, eidx, row_ptr,
        msgbuf);
    gru_kernel<<<NNODES / 64, 256, 0, stream>>>(hstate, msgbuf, row_ptr,
                                                WxH, WhH, bxf, bhf, bconvf);
  }
  s2s6_kernel<<<NGRAPH / 4, 512, 0, stream>>>(dflag, hstate,
      (const float4*)LWf, lstm_bsum,
      Wout1, bout1, Wout2, bout2, (float*)d_out);
}

// Round 5
// 1331.595 us; speedup vs baseline: 1.4867x; 1.4867x over previous
//
#include <hip/hip_runtime.h>

// ---------- types / helpers ----------
typedef __attribute__((ext_vector_type(8))) _Float16 f16x8;
typedef __attribute__((ext_vector_type(4))) float floatx4;

union HFrag { uint4 u4; f16x8 v; unsigned short s[8]; };
union HS { _Float16 h; unsigned short u; };

__device__ __forceinline__ float bf2f(unsigned short u) {
  return __uint_as_float(((unsigned int)u) << 16);
}
__device__ __forceinline__ float h2f(unsigned short u) { HS z; z.u = u; return (float)z.h; }
__device__ __forceinline__ unsigned short f2h(float f) { HS z; z.h = (_Float16)f; return z.u; }
__device__ __forceinline__ float sigmf(float x) { return 1.0f / (1.0f + expf(-x)); }

// dtype-agnostic input load: f32 ? float : bf16
__device__ __forceinline__ float ldi(const void* p, long i, bool f32) {
  return f32 ? ((const float*)p)[i] : bf2f(((const unsigned short*)p)[i]);
}

// async global->LDS DMA, 16B per lane. LDS dest = wave-uniform base + lane*16.
__device__ __forceinline__ void dma16(unsigned short* lds, const unsigned short* g) {
  __builtin_amdgcn_global_load_lds(
      (const __attribute__((address_space(1))) unsigned int*)g,
      (__attribute__((address_space(3))) unsigned int*)lds,
      16, 0, 0);
}

// wave-local waits (gfx9 encoding: vm [3:0]|[15:14], exp [6:4], lgkm [11:8])
#define WAIT_VM2()   __builtin_amdgcn_s_waitcnt(0x0F72)
#define WAIT_VM0()   __builtin_amdgcn_s_waitcnt(0x0F70)
#define WAIT_LGKM0() __builtin_amdgcn_s_waitcnt(0xC07F)

// barrier that does NOT drain vmcnt (keeps DMA pipeline alive across it)
#define SAFE_BARRIER() do {                      \
  __builtin_amdgcn_sched_barrier(0);             \
  WAIT_LGKM0();                                  \
  __builtin_amdgcn_s_barrier();                  \
  __builtin_amdgcn_sched_barrier(0);             \
} while (0)

#define NNODES 32000
#define NEDGES 80000
#define NGRAPH 1000

#define MFMA_F16 __builtin_amdgcn_mfma_f32_16x16x32_f16

// ---------- dtype detect ----------
__global__ __launch_bounds__(256) void detect_kernel(
    const unsigned short* __restrict__ nf, int* __restrict__ flag) {
  __shared__ float sm[256];
  float m = 0.f;
  for (int i = threadIdx.x; i < 4096; i += 256) {
    float v = fabsf(bf2f(nf[i]));
    if (isfinite(v)) m = fmaxf(m, v);
    else m = 1e30f;
  }
  sm[threadIdx.x] = m;
  __syncthreads();
  if (threadIdx.x == 0) {
    float mm = 0.f;
    for (int i = 0; i < 256; ++i) mm = fmaxf(mm, sm[i]);
    flag[0] = (mm > 1e6f) ? 1 : 0;
  }
}

// ---------- prep: GRU weights -> fp16 [192][64] (j-major, transposed) ----------
__global__ __launch_bounds__(256) void prep_kernel(
    const int* __restrict__ dflag,
    const void* __restrict__ Wx, const void* __restrict__ Wh,
    const void* __restrict__ bx, const void* __restrict__ bh,
    const void* __restrict__ bconv,
    unsigned short* __restrict__ WxH, unsigned short* __restrict__ WhH,
    float* __restrict__ bxf, float* __restrict__ bhf, float* __restrict__ bconvf) {
  bool f32 = dflag[0] != 0;
  int idx = blockIdx.x * 256 + threadIdx.x;   // grid 48 -> 12288 = 192*64
  int j = idx >> 6, k = idx & 63;
  WxH[idx] = f2h(ldi(Wx, k * 192 + j, f32));
  WhH[idx] = f2h(ldi(Wh, k * 192 + j, f32));
  if (idx < 192) { bxf[idx] = ldi(bx, idx, f32); bhf[idx] = ldi(bh, idx, f32); }
  if (idx < 64) bconvf[idx] = ldi(bconv, idx, f32);
}

// ---------- prep: LSTM weights -> chunk-major float4 [chunk][gate] ----------
__global__ __launch_bounds__(256) void lstmprep_kernel(
    const int* __restrict__ dflag,
    const void* Wx0, const void* Wh0, const void* bx0, const void* bh0,
    const void* Wx1, const void* Wh1, const void* bx1, const void* bh1,
    const void* Wx2, const void* Wh2, const void* bx2, const void* bh2,
    float4* __restrict__ LW, float* __restrict__ bsum) {
  bool f32 = dflag[0] != 0;
  int idx = blockIdx.x * 256 + threadIdx.x;   // grid 112 -> 28672 float4
  int l, base, fi;
  if (idx < 12288)      { l = 0; base = 0;     fi = 128; }
  else if (idx < 20480) { l = 1; base = 12288; fi = 64; }
  else                  { l = 2; base = 20480; fi = 64; }
  const void* Wx = (l == 0) ? Wx0 : (l == 1) ? Wx1 : Wx2;
  const void* Wh = (l == 0) ? Wh0 : (l == 1) ? Wh1 : Wh2;
  int r = idx - base;
  int c = r >> 8, t = r & 255;
  float v[4];
#pragma unroll
  for (int i2 = 0; i2 < 4; ++i2) {
    int k = c * 4 + i2;
    v[i2] = (k < fi) ? ldi(Wx, (long)k * 256 + t, f32)
                     : ldi(Wh, (long)(k - fi) * 256 + t, f32);
  }
  float4 o; o.x = v[0]; o.y = v[1]; o.z = v[2]; o.w = v[3];
  LW[idx] = o;
  if (idx < 768) {
    int ll = idx >> 8, j = idx & 255;
    const void* bx = (ll == 0) ? bx0 : (ll == 1) ? bx1 : bx2;
    const void* bh = (ll == 0) ? bh0 : (ll == 1) ? bh1 : bh2;
    bsum[idx] = ldi(bx, j, f32) + ldi(bh, j, f32);
  }
}

// ---------- node projection: h = relu(nf @ Wp + bp) ----------
__global__ __launch_bounds__(256) void nodeproj_kernel(
    const int* __restrict__ dflag,
    const void* __restrict__ nf, const void* __restrict__ Wp,
    const void* __restrict__ bp, float* __restrict__ hstate) {
  bool f32 = dflag[0] != 0;
  int lane = threadIdx.x & 63;
  int n = blockIdx.x * 4 + (threadIdx.x >> 6);
  float acc = ldi(bp, lane, f32);
  for (int k = 0; k < 74; ++k)
    acc += ldi(nf, (long)n * 74 + k, f32) * ldi(Wp, k * 64 + lane, f32);
  hstate[n * 64 + lane] = fmaxf(acc, 0.0f);
}

// ---------- We2T: fp16 Bt tiles, per-k: [k 128][o 64][g' 8][j 8] ----------
// g' = g ^ (o&7), d = g*8 + j; value = We2[k][d*64 + o]
__global__ __launch_bounds__(256) void we2t_kernel(
    const int* __restrict__ dflag,
    const void* __restrict__ We2, unsigned short* __restrict__ We2T) {
  bool f32 = dflag[0] != 0;
  int idx = blockIdx.x * 256 + threadIdx.x;  // grid 2048 -> 524288
  int j = idx & 7;
  int gs = (idx >> 3) & 7;
  int o = (idx >> 6) & 63;
  int k = idx >> 12;                          // 0..127
  int g = gs ^ (o & 7);
  int d = g * 8 + j;
  We2T[idx] = f2h(ldi(We2, (long)k * 4096 + d * 64 + o, f32));
}

// ---------- be2T: fp16 Bt for hbe GEMM: [o 64][g' 8][j 8], g' = g^(o&7) ----
__global__ __launch_bounds__(256) void be2t_kernel(
    const int* __restrict__ dflag,
    const void* __restrict__ be2, unsigned short* __restrict__ be2T) {
  bool f32 = dflag[0] != 0;
  int idx = blockIdx.x * 256 + threadIdx.x;  // grid 16 -> 4096
  int j = idx & 7;
  int gs = (idx >> 3) & 7;
  int o = idx >> 6;
  int g = gs ^ (o & 7);
  int d = g * 8 + j;
  be2T[idx] = f2h(ldi(be2, (long)d * 64 + o, f32));
}

// ---------- CSR build (once per launch; dst is launch-invariant) ----------
__global__ __launch_bounds__(256) void count_kernel(
    const int* __restrict__ dst, int* __restrict__ cnt) {
  int e = blockIdx.x * 256 + threadIdx.x;
  if (e < NEDGES) atomicAdd(&cnt[dst[e]], 1);
}

__global__ __launch_bounds__(256) void scan_kernel(
    const int* __restrict__ cnt, int* __restrict__ row_ptr, int* __restrict__ cur) {
  __shared__ int part[256];
  int t = threadIdx.x;
  int base = t * 125;              // 256*125 = 32000
  int s = 0;
  for (int i = 0; i < 125; ++i) s += cnt[base + i];
  part[t] = s;
  __syncthreads();
  if (t == 0) {
    int run = 0;
    for (int i = 0; i < 256; ++i) { int v = part[i]; part[i] = run; run += v; }
  }
  __syncthreads();
  int run = part[t];
  for (int i = 0; i < 125; ++i) {
    row_ptr[base + i] = run;
    cur[base + i] = run;
    run += cnt[base + i];
  }
  if (t == 255) row_ptr[32000] = run;
}

__global__ __launch_bounds__(256) void fill_kernel(
    const int* __restrict__ dst, int* __restrict__ cur, int* __restrict__ eidx) {
  int e = blockIdx.x * 256 + threadIdx.x;
  if (e < NEDGES) { int p = atomicAdd(&cur[dst[e]], 1); eidx[p] = e; }
}

// ---------- message passing, nodes-first (Z), v2 ----------
// Swapped GEMM per k-chunk (1 k): Zk[o][n] = sum_d Bt[o][d] * h[n][d].
// Wave w owns o-rows [w*16, w*16+16): Bt stream fully wave-private (DMA
// quarter == frag rows, no barriers on Bt). Z stored [node][o] f32 with
// padded stride 76 (19*16B, 19 coprime 8 -> even bank quads for random-r
// edge reads). h fragments cached in registers. LDS 80.4 KB -> 2 blocks/CU.
__global__ __launch_bounds__(256, 2) void msg_z_kernel(
    const int* __restrict__ dflag,
    const float* __restrict__ hstate,
    const void* __restrict__ ef, const void* __restrict__ We1,
    const void* __restrict__ be1,
    const unsigned short* __restrict__ We2T,
    const unsigned short* __restrict__ be2T,
    const int* __restrict__ src, const int* __restrict__ eidx,
    const int* __restrict__ row_ptr,
    float* __restrict__ msgbuf) {
  bool f32 = dflag[0] != 0;
  __shared__ __align__(16) unsigned short hhi[64][72];   //  9216 B
  __shared__ __align__(16) unsigned short hlo[64][72];   //  9216 B
  __shared__ __align__(16) unsigned short BtL[2][4096];  // 16384 B (dbuf, 1 k)
  __shared__ __align__(16) float Zs[2][64][76];          // 38912 B (dbuf, pad)
  __shared__ float we1T_s[1536];                         //  6144 B [k][j]
  __shared__ float be1_s[128];                           //   512 B
  // total 80384 B -> 2 blocks/CU

  int t = threadIdx.x, lane = t & 63, w = t >> 6;
  int c16 = lane & 15, q = lane >> 4;
  int nb = blockIdx.x * 64;                              // 500 blocks
  int p0 = row_ptr[nb], p1 = row_ptr[nb + 64];
  int nE = p1 - p0;
  if (nE <= 0) return;

  // ---- stage h (hi/lo fp16), we1 transposed, be1 ----
  for (int i = t; i < 4096; i += 256) {
    int n = i >> 6, cc = i & 63;
    float v = hstate[(size_t)(nb + n) * 64 + cc];
    HS hi; hi.h = (_Float16)v;
    hhi[n][cc] = hi.u;
    hlo[n][cc] = f2h(v - (float)hi.h);
  }
  for (int i = t; i < 1536; i += 256) {
    int k = i / 12, j = i - k * 12;
    we1T_s[i] = ldi(We1, j * 128 + k, f32);              // We1 is [12][128]
  }
  if (t < 128) be1_s[t] = ldi(be1, t, f32);
  __syncthreads();

  // ---- cache h fragments (B-operand) in registers: never re-read in loop ----
  HFrag bhi[4][2], blo[4][2];
#pragma unroll
  for (int nt = 0; nt < 4; ++nt)
#pragma unroll
    for (int ks = 0; ks < 2; ++ks) {
      bhi[nt][ks].u4 = *(const uint4*)&hhi[nt * 16 + c16][ks * 32 + q * 8];
      blo[nt][ks].u4 = *(const uint4*)&hlo[nt * 16 + c16][ks * 32 + q * 8];
    }

  int arow = (w * 16 + c16) * 64;          // A-frag row base (shorts) in BtL
  int g0q = (q ^ (c16 & 7)) * 8;           // ks=0 granule offset
  int g1q = ((4 + q) ^ (c16 & 7)) * 8;     // ks=1 granule offset

  // ---- edge tiles of 256 (virtually always a single tile) ----
  for (int et = 0; et < nE; et += 256) {
    if (et > 0) SAFE_BARRIER();            // prev tile's Zs readers done
    int me = et + t;
    bool act = me < nE;
    int pos = p0 + (act ? me : 0);
    int eg = eidx[pos];
    int r = src[eg] - nb;                  // 0..63 (in-graph edges)
    float efr[12];
#pragma unroll
    for (int j = 0; j < 12; ++j) efr[j] = ldi(ef, (long)eg * 12 + j, f32);

    // ---- DMA beT -> BtL[0], k0 -> BtL[1] (wave-private quarters) ----
    dma16(&BtL[0][0] + w * 1024, be2T + w * 1024 + lane * 8);
    dma16(&BtL[0][0] + w * 1024 + 512, be2T + w * 1024 + 512 + lane * 8);
    dma16(&BtL[1][0] + w * 1024, We2T + w * 1024 + lane * 8);
    dma16(&BtL[1][0] + w * 1024 + 512, We2T + w * 1024 + 512 + lane * 8);
    WAIT_VM0();                            // edge regs + beT + k0 all ready

    // ---- hbe[o][n] = sum_d be2T[o][d] * h[n][d] ----
    floatx4 hacc[4];
#pragma unroll
    for (int nt = 0; nt < 4; ++nt) hacc[nt] = (floatx4){0.f, 0.f, 0.f, 0.f};
    {
      HFrag aB0, aB1;
      aB0.u4 = *(const uint4*)&BtL[0][arow + g0q];
      aB1.u4 = *(const uint4*)&BtL[0][arow + g1q];
#pragma unroll
      for (int nt = 0; nt < 4; ++nt) {
        hacc[nt] = MFMA_F16(aB0.v, bhi[nt][0].v, hacc[nt], 0, 0, 0);
        hacc[nt] = MFMA_F16(aB0.v, blo[nt][0].v, hacc[nt], 0, 0, 0);
        hacc[nt] = MFMA_F16(aB1.v, bhi[nt][1].v, hacc[nt], 0, 0, 0);
        hacc[nt] = MFMA_F16(aB1.v, blo[nt][1].v, hacc[nt], 0, 0, 0);
      }
    }
    __builtin_amdgcn_sched_barrier(0);
    WAIT_LGKM0();                          // beT frag reads done
    __builtin_amdgcn_sched_barrier(0);
    // k1 -> BtL[0] (overwrites beT; safe: wave-private rows, reads drained)
    dma16(&BtL[0][0] + w * 1024, We2T + 4096 + w * 1024 + lane * 8);
    dma16(&BtL[0][0] + w * 1024 + 512, We2T + 4096 + w * 1024 + 512 + lane * 8);
    // store hbe -> Zs[1] as [n][o]
#pragma unroll
    for (int nt = 0; nt < 4; ++nt) {
      float4 st;
      st.x = hacc[nt][0]; st.y = hacc[nt][1]; st.z = hacc[nt][2]; st.w = hacc[nt][3];
      *(float4*)&Zs[1][nt * 16 + c16][w * 16 + q * 4] = st;
    }
    SAFE_BARRIER();                        // Zs[1] (hbe) visible

    // ---- msg init from hbe ----
    floatx4 msgv[16];
    if (act) {
#pragma unroll
      for (int og = 0; og < 16; ++og)
        msgv[og] = *(const floatx4*)&Zs[1][r][og * 4];
    }

    // ---- k-chunk loop: 128 chunks x 1 k ----
    for (int c = 0; c < 128; ++c) {
      int cb = (c + 1) & 1;                // chunk c lives in BtL[cb]
      if (c == 127) WAIT_VM0(); else WAIT_VM2();
      HFrag aB0, aB1;
      aB0.u4 = *(const uint4*)&BtL[cb][arow + g0q];
      aB1.u4 = *(const uint4*)&BtL[cb][arow + g1q];
      __builtin_amdgcn_sched_barrier(0);
      WAIT_LGKM0();                        // frags in regs before buffer reuse
      __builtin_amdgcn_sched_barrier(0);
      if (c + 2 < 128) {                   // prefetch k(c+2) into freed buffer
        const unsigned short* G = We2T + (c + 2) * 4096 + w * 1024 + lane * 8;
        dma16(&BtL[cb][0] + w * 1024, G);
        dma16(&BtL[cb][0] + w * 1024 + 512, G + 512);
      }
      floatx4 zacc[4];
#pragma unroll
      for (int nt = 0; nt < 4; ++nt) zacc[nt] = (floatx4){0.f, 0.f, 0.f, 0.f};
#pragma unroll
      for (int nt = 0; nt < 4; ++nt) {
        zacc[nt] = MFMA_F16(aB0.v, bhi[nt][0].v, zacc[nt], 0, 0, 0);
        zacc[nt] = MFMA_F16(aB0.v, blo[nt][0].v, zacc[nt], 0, 0, 0);
        zacc[nt] = MFMA_F16(aB1.v, bhi[nt][1].v, zacc[nt], 0, 0, 0);
        zacc[nt] = MFMA_F16(aB1.v, blo[nt][1].v, zacc[nt], 0, 0, 0);
      }
#pragma unroll
      for (int nt = 0; nt < 4; ++nt) {
        float4 st;
        st.x = zacc[nt][0]; st.y = zacc[nt][1]; st.z = zacc[nt][2]; st.w = zacc[nt][3];
        *(float4*)&Zs[c & 1][nt * 16 + c16][w * 16 + q * 4] = st;
      }
      SAFE_BARRIER();                      // Z(c) visible; prev buf readers done

      // edge pass: u[e][c] (f32, recomputed) x Z rows
      if (act) {
        float u = be1_s[c];
#pragma unroll
        for (int j = 0; j < 12; ++j) u += efr[j] * we1T_s[c * 12 + j];
        u = fmaxf(u, 0.f);
#pragma unroll
        for (int og = 0; og < 16; ++og) {
          floatx4 z = *(const floatx4*)&Zs[c & 1][r][og * 4];
          msgv[og] += u * z;
        }
      }
    }

    // ---- store msg (CSR position order, same contract as before) ----
    if (act) {
      float* mp = msgbuf + (size_t)pos * 64;
#pragma unroll
      for (int og = 0; og < 16; ++og) *(floatx4*)(mp + og * 4) = msgv[og];
    }
  }
}

// ---------- GRU step: MFMA gates (fp16, X hi/lo split) + fused CSR gather ------
__global__ __launch_bounds__(256, 2) void gru_kernel(
    float* __restrict__ hstate, const float* __restrict__ msgbuf,
    const int* __restrict__ row_ptr,
    const unsigned short* __restrict__ WxH, const unsigned short* __restrict__ WhH,
    const float* __restrict__ bxf, const float* __restrict__ bhf,
    const float* __restrict__ bconvf) {
  __shared__ __align__(16) unsigned short Xhi[64][72];   // 9216 B
  __shared__ __align__(16) unsigned short Xlo[64][72];   // 9216 B
  __shared__ __align__(16) unsigned short Hh[64][72];    // 9216 B
  __shared__ unsigned short SRZ[128][68];                // 17408 B (fp16 sig(r/z))
  __shared__ float GXn[64][66];                          // 16896 B
  __shared__ float GHn[64][66];                          // 16896 B
  int t = threadIdx.x;
  int nb = blockIdx.x * 64;                              // 500 blocks

#pragma unroll
  for (int i = 0; i < 16; ++i) {
    int idx = t + i * 256;
    int n = idx >> 6, c = idx & 63;
    int node = nb + n;
    float a = bconvf[c];
    int p0 = row_ptr[node], p1 = row_ptr[node + 1];
    for (int p = p0; p < p1; ++p) a += msgbuf[(size_t)p * 64 + c];
    a = fmaxf(a, 0.f);
    HS hi; hi.h = (_Float16)a;
    Xhi[n][c] = hi.u;
    Xlo[n][c] = f2h(a - (float)hi.h);
    Hh[n][c] = f2h(hstate[(size_t)node * 64 + c]);
  }
  __syncthreads();

  int lane = t & 63, w = t >> 6;
  int c16 = lane & 15, q = lane >> 4;
  floatx4 gx[3][4], gh[3][4];
#pragma unroll
  for (int jt = 0; jt < 3; ++jt)
#pragma unroll
    for (int nt = 0; nt < 4; ++nt) {
      gx[jt][nt] = (floatx4){0.f, 0.f, 0.f, 0.f};
      gh[jt][nt] = (floatx4){0.f, 0.f, 0.f, 0.f};
    }
#pragma unroll
  for (int kc = 0; kc < 2; ++kc) {
    int kof = kc * 32 + q * 8;
    HFrag ax[3], ah[3];
#pragma unroll
    for (int jt = 0; jt < 3; ++jt) {
      long off = (long)((w * 3 + jt) * 16 + c16) * 64 + kof;
      ax[jt].u4 = *(const uint4*)(WxH + off);
      ah[jt].u4 = *(const uint4*)(WhH + off);
    }
    HFrag bxh[4], bxl[4], bhf_[4];
#pragma unroll
    for (int nt = 0; nt < 4; ++nt) {
      int n = nt * 16 + c16;
      bxh[nt].u4 = *(const uint4*)&Xhi[n][kof];
      bxl[nt].u4 = *(const uint4*)&Xlo[n][kof];
      bhf_[nt].u4 = *(const uint4*)&Hh[n][kof];
    }
#pragma unroll
    for (int jt = 0; jt < 3; ++jt)
#pragma unroll
      for (int nt = 0; nt < 4; ++nt) {
        gx[jt][nt] = MFMA_F16(ax[jt].v, bxh[nt].v, gx[jt][nt], 0, 0, 0);
        gx[jt][nt] = MFMA_F16(ax[jt].v, bxl[nt].v, gx[jt][nt], 0, 0, 0);
        gh[jt][nt] = MFMA_F16(ah[jt].v, bhf_[nt].v, gh[jt][nt], 0, 0, 0);
      }
  }

#pragma unroll
  for (int jt = 0; jt < 3; ++jt) {
#pragma unroll
    for (int rr = 0; rr < 4; ++rr) {
      int j = (w * 3 + jt) * 16 + q * 4 + rr;
      float bxv = bxf[j], bhv = bhf[j];
#pragma unroll
      for (int nt = 0; nt < 4; ++nt) {
        int n = nt * 16 + c16;
        float vx = gx[jt][nt][rr] + bxv;
        float vh = gh[jt][nt][rr] + bhv;
        if (j < 128) {
          SRZ[j][n] = f2h(sigmf(vx + vh));
        } else {
          GXn[j - 128][n] = vx;
          GHn[j - 128][n] = vh;
        }
      }
    }
  }
  __syncthreads();

#pragma unroll
  for (int i = 0; i < 16; ++i) {
    int idx = t + i * 256;
    int n = idx >> 6, f = idx & 63;
    float r = h2f(SRZ[f][n]);
    float z = h2f(SRZ[64 + f][n]);
    float ng = tanhf(GXn[f][n] + r * GHn[f][n]);
    size_t gi = (size_t)(nb + n) * 64 + f;
    float ho = hstate[gi];
    hstate[gi] = (1.0f - z) * ng + z * ho;
  }
}

// ---------- Set2Set fused x6 + head ----------
__global__ __launch_bounds__(512) void s2s6_kernel(
    const int* __restrict__ dflag,
    const float* __restrict__ hstate,
    const float4* __restrict__ LW,        // [l0:48|l1:32|l2:32] x 256 float4
    const float* __restrict__ lstm_bsum,  // [3][256] bx+bh
    const void* __restrict__ Wout1, const void* __restrict__ bout1,
    const void* __restrict__ Wout2, const void* __restrict__ bout2,
    float* __restrict__ out) {
  bool f32 = dflag[0] != 0;
  __shared__ float xq[4][128];        // q_star per graph
  __shared__ float inb[4][192];       // combined [xq(fi) | h(64)] per graph
  __shared__ float gates[4][256];
  __shared__ float al[4][32];
  __shared__ float hsvf[768];         // 3 layers x 4 graphs x 64
  __shared__ float csvf[768];
  int g0 = blockIdx.x * 4;
  int t = threadIdx.x;

  for (int i = t; i < 512; i += 512) xq[i >> 7][i & 127] = 0.f;
  for (int i = t; i < 768; i += 512) { hsvf[i] = 0.f; csvf[i] = 0.f; }
  __syncthreads();

  int tt = t & 255, gp = t >> 8;      // gate id, graph-pair
  int ga = gp * 2, gb = ga + 1;

  for (int s = 0; s < 6; ++s) {
#pragma unroll
    for (int l = 0; l < 3; ++l) {
      const int fi = (l == 0) ? 128 : 64;
      const int tot = fi + 64;
      for (int i = t; i < 4 * tot; i += 512) {
        int g = i / tot, k = i - g * tot;
        inb[g][k] = (k < fi) ? xq[g][k] : hsvf[l * 256 + g * 64 + (k - fi)];
      }
      __syncthreads();
      const int nch = tot >> 2;
      const float4* wrow = LW + ((l == 0) ? 0 : (l == 1) ? 12288 : 20480) + tt;
      float bs = lstm_bsum[l * 256 + tt];
      float a0 = bs, a1 = bs;
#pragma unroll 8
      for (int cch = 0; cch < nch; ++cch) {
        float4 wv = wrow[(size_t)cch * 256];
        float4 x0 = *(const float4*)&inb[ga][cch * 4];
        float4 x1 = *(const float4*)&inb[gb][cch * 4];
        a0 += wv.x * x0.x + wv.y * x0.y + wv.z * x0.z + wv.w * x0.w;
        a1 += wv.x * x1.x + wv.y * x1.y + wv.z * x1.z + wv.w * x1.w;
      }
      gates[ga][tt] = a0;
      gates[gb][tt] = a1;
      __syncthreads();
      if (t < 256) {
        int gg = t >> 6, u = t & 63;
        float ig = sigmf(gates[gg][u]);
        float fg = sigmf(gates[gg][64 + u]);
        float gv = tanhf(gates[gg][128 + u]);
        float og = sigmf(gates[gg][192 + u]);
        int ci = l * 256 + t;
        float cc = fg * csvf[ci] + ig * gv;
        float hn = og * tanhf(cc);
        csvf[ci] = cc;
        hsvf[ci] = hn;
        xq[gg][u] = hn;
      }
      __syncthreads();
    }
    if (t < 256) {
      int gg = t >> 6, tl = t & 63;
      int g = g0 + gg;
      int n = tl & 31, half = tl >> 5;
      const float* hrow = hstate + (size_t)(g * 32 + n) * 64 + half * 32;
      const float* qp = &xq[gg][half * 32];
      float p = 0.f;
#pragma unroll
      for (int k = 0; k < 32; ++k) p += hrow[k] * qp[k];
      p += __shfl_xor(p, 32, 64);
      if (half == 0) {
        float m = p;
#pragma unroll
        for (int s2 = 1; s2 < 32; s2 <<= 1) m = fmaxf(m, __shfl_xor(m, s2, 32));
        float e = expf(p - m);
        float sum = e;
#pragma unroll
        for (int s2 = 1; s2 < 32; s2 <<= 1) sum += __shfl_xor(sum, s2, 32);
        al[gg][n] = e / sum;
      }
      float acc = 0.f;
#pragma unroll 8
      for (int nn = 0; nn < 32; ++nn)
        acc += al[gg][nn] * hstate[(size_t)(g * 32 + nn) * 64 + tl];
      xq[gg][64 + tl] = acc;
    }
    __syncthreads();
  }

  if (t < 256) {
    int gg = t >> 6, tl = t & 63;
    int g = g0 + gg;
    float acc = ldi(bout1, tl, f32);
#pragma unroll 16
    for (int k = 0; k < 128; ++k) acc += xq[gg][k] * ldi(Wout1, k * 64 + tl, f32);
    acc = fmaxf(acc, 0.0f);
    float p = acc * ldi(Wout2, tl, f32);
#pragma unroll
    for (int m = 1; m < 64; m <<= 1) p += __shfl_xor(p, m, 64);
    if (tl == 0) out[g] = p + ldi(bout2, 0, f32);
    out[1000 + g * 128 + tl] = xq[gg][tl];
    out[1000 + g * 128 + 64 + tl] = xq[gg][64 + tl];
  }
}

// ---------- launch ----------
extern "C" void kernel_launch(void* const* d_in, const int* in_sizes, int n_in,
                              void* d_out, int out_size, void* d_ws, size_t ws_size,
                              hipStream_t stream) {
  (void)in_sizes; (void)n_in; (void)out_size; (void)ws_size;
  const void* node_feats = d_in[0];
  const void* edge_feats = d_in[1];
  const int* src = (const int*)d_in[2];
  const int* dst = (const int*)d_in[3];
  const void* Wp = d_in[5];
  const void* bp = d_in[6];
  const void* We1 = d_in[7];
  const void* be1 = d_in[8];
  const void* We2 = d_in[9];
  const void* be2 = d_in[10];
  const void* b_conv = d_in[11];
  const void* gWx = d_in[12];
  const void* gWh = d_in[13];
  const void* gbx = d_in[14];
  const void* gbh = d_in[15];
  const void* Wout1 = d_in[16];
  const void* bout1 = d_in[17];
  const void* Wout2 = d_in[18];
  const void* bout2 = d_in[19];

  // workspace layout (~31.9 MB; proven-mapped region >= 44.5 MB)
  int* dflag = (int*)d_ws;                                    // 64 ints reserved
  float* hstate = (float*)d_ws + 64;                          // 32000*64 f32
  float* msgbuf = hstate + NNODES * 64;                       // 80000*64 f32
  unsigned short* We2T = (unsigned short*)(msgbuf + (size_t)NEDGES * 64); // 524288 fp16
  unsigned short* WxH = We2T + 524288;                        // 12288 fp16
  unsigned short* WhH = WxH + 12288;                          // 12288 fp16
  float* bxf = (float*)(WhH + 12288);                         // 192
  float* bhf = bxf + 192;                                     // 192
  float* bconvf = bhf + 192;                                  // 64
  int* row_ptr = (int*)(bconvf + 64);                         // 32001
  int* cur = row_ptr + 32001;                                 // 32000
  int* cnt = cur + 32000;                                     // 32000
  int* eidx = cnt + 32000;                                    // 80000
  uintptr_t lwp = (uintptr_t)(eidx + 80000);
  lwp = (lwp + 15) & ~(uintptr_t)15;                          // 16B align
  float4* LWf = (float4*)lwp;                                 // 28672 float4 (448 KB)
  float* lstm_bsum = (float*)(LWf + 28672);                   // 768 f32
  unsigned short* be2T = (unsigned short*)(lstm_bsum + 768);  // 4096 fp16

  (void)hipMemsetAsync(cnt, 0, (size_t)NNODES * sizeof(int), stream);

  detect_kernel<<<1, 256, 0, stream>>>((const unsigned short*)node_feats, dflag);
  prep_kernel<<<48, 256, 0, stream>>>(dflag, gWx, gWh, gbx, gbh, b_conv,
                                      WxH, WhH, bxf, bhf, bconvf);
  nodeproj_kernel<<<NNODES / 4, 256, 0, stream>>>(dflag, node_feats, Wp, bp, hstate);
  we2t_kernel<<<2048, 256, 0, stream>>>(dflag, We2, We2T);
  be2t_kernel<<<16, 256, 0, stream>>>(dflag, be2, be2T);
  lstmprep_kernel<<<112, 256, 0, stream>>>(dflag,
      d_in[20], d_in[21], d_in[22], d_in[23],
      d_in[24], d_in[25], d_in[26], d_in[27],
      d_in[28], d_in[29], d_in[30], d_in[31],
      LWf, lstm_bsum);

  count_kernel<<<(NEDGES + 255) / 256, 256, 0, stream>>>(dst, cnt);
  scan_kernel<<<1, 256, 0, stream>>>(cnt, row_ptr, cur);
  fill_kernel<<<(NEDGES + 255) / 256, 256, 0, stream>>>(dst, cur, eidx);

  for (int step = 0; step < 6; ++step) {
    msg_z_kernel<<<NNODES / 64, 256, 0, stream>>>(
        dflag, hstate, edge_feats, We1, be1, We2T, be2T, src, eidx, row_ptr,
        msgbuf);
    gru_kernel<<<NNODES / 64, 256, 0, stream>>>(hstate, msgbuf, row_ptr,
                                                WxH, WhH, bxf, bhf, bconvf);
  }
  s2s6_kernel<<<NGRAPH / 4, 512, 0, stream>>>(dflag, hstate,
      (const float4*)LWf, lstm_bsum,
      Wout1, bout1, Wout2, bout2, (float*)d_out);
}

// Round 6
// 1181.201 us; speedup vs baseline: 1.6760x; 1.1273x over previous
//
#include <hip/hip_runtime.h>

// ---------- types / helpers ----------
typedef __attribute__((ext_vector_type(8))) _Float16 f16x8;
typedef __attribute__((ext_vector_type(2))) _Float16 f16x2;
typedef __attribute__((ext_vector_type(4))) float floatx4;

union HFrag { uint4 u4; f16x8 v; unsigned short s[8]; };
union HS { _Float16 h; unsigned short u; };
union UH2 { unsigned int u; f16x2 h; };

__device__ __forceinline__ float bf2f(unsigned short u) {
  return __uint_as_float(((unsigned int)u) << 16);
}
__device__ __forceinline__ float h2f(unsigned short u) { HS z; z.u = u; return (float)z.h; }
__device__ __forceinline__ unsigned short f2h(float f) { HS z; z.h = (_Float16)f; return z.u; }
__device__ __forceinline__ float sigmf(float x) { return 1.0f / (1.0f + expf(-x)); }

// dtype-agnostic input load: f32 ? float : bf16
__device__ __forceinline__ float ldi(const void* p, long i, bool f32) {
  return f32 ? ((const float*)p)[i] : bf2f(((const unsigned short*)p)[i]);
}

// async global->LDS DMA, 16B per lane. LDS dest = wave-uniform base + lane*16.
__device__ __forceinline__ void dma16(unsigned short* lds, const unsigned short* g) {
  __builtin_amdgcn_global_load_lds(
      (const __attribute__((address_space(1))) unsigned int*)g,
      (__attribute__((address_space(3))) unsigned int*)lds,
      16, 0, 0);
}

// wave-local waits (gfx9 encoding: vm [3:0]|[15:14], exp [6:4], lgkm [11:8])
#define WAIT_VM4()   __builtin_amdgcn_s_waitcnt(0x0F74)
#define WAIT_VM0()   __builtin_amdgcn_s_waitcnt(0x0F70)
#define WAIT_LGKM0() __builtin_amdgcn_s_waitcnt(0xC07F)

// barrier that does NOT drain vmcnt (keeps DMA pipeline alive across it)
#define SAFE_BARRIER() do {                      \
  __builtin_amdgcn_sched_barrier(0);             \
  WAIT_LGKM0();                                  \
  __builtin_amdgcn_s_barrier();                  \
  __builtin_amdgcn_sched_barrier(0);             \
} while (0)

#define NNODES 32000
#define NEDGES 80000
#define NGRAPH 1000

#define MFMA_F16 __builtin_amdgcn_mfma_f32_16x16x32_f16

// ---------- dtype detect ----------
__global__ __launch_bounds__(256) void detect_kernel(
    const unsigned short* __restrict__ nf, int* __restrict__ flag) {
  __shared__ float sm[256];
  float m = 0.f;
  for (int i = threadIdx.x; i < 4096; i += 256) {
    float v = fabsf(bf2f(nf[i]));
    if (isfinite(v)) m = fmaxf(m, v);
    else m = 1e30f;
  }
  sm[threadIdx.x] = m;
  __syncthreads();
  if (threadIdx.x == 0) {
    float mm = 0.f;
    for (int i = 0; i < 256; ++i) mm = fmaxf(mm, sm[i]);
    flag[0] = (mm > 1e6f) ? 1 : 0;
  }
}

// ---------- prep: GRU weights -> fp16 [192][64] (j-major, transposed) ----------
__global__ __launch_bounds__(256) void prep_kernel(
    const int* __restrict__ dflag,
    const void* __restrict__ Wx, const void* __restrict__ Wh,
    const void* __restrict__ bx, const void* __restrict__ bh,
    const void* __restrict__ bconv,
    unsigned short* __restrict__ WxH, unsigned short* __restrict__ WhH,
    float* __restrict__ bxf, float* __restrict__ bhf, float* __restrict__ bconvf) {
  bool f32 = dflag[0] != 0;
  int idx = blockIdx.x * 256 + threadIdx.x;   // grid 48 -> 12288 = 192*64
  int j = idx >> 6, k = idx & 63;
  WxH[idx] = f2h(ldi(Wx, k * 192 + j, f32));
  WhH[idx] = f2h(ldi(Wh, k * 192 + j, f32));
  if (idx < 192) { bxf[idx] = ldi(bx, idx, f32); bhf[idx] = ldi(bh, idx, f32); }
  if (idx < 64) bconvf[idx] = ldi(bconv, idx, f32);
}

// ---------- prep: LSTM weights -> chunk-major float4 [chunk][gate] ----------
__global__ __launch_bounds__(256) void lstmprep_kernel(
    const int* __restrict__ dflag,
    const void* Wx0, const void* Wh0, const void* bx0, const void* bh0,
    const void* Wx1, const void* Wh1, const void* bx1, const void* bh1,
    const void* Wx2, const void* Wh2, const void* bx2, const void* bh2,
    float4* __restrict__ LW, float* __restrict__ bsum) {
  bool f32 = dflag[0] != 0;
  int idx = blockIdx.x * 256 + threadIdx.x;   // grid 112 -> 28672 float4
  int l, base, fi;
  if (idx < 12288)      { l = 0; base = 0;     fi = 128; }
  else if (idx < 20480) { l = 1; base = 12288; fi = 64; }
  else                  { l = 2; base = 20480; fi = 64; }
  const void* Wx = (l == 0) ? Wx0 : (l == 1) ? Wx1 : Wx2;
  const void* Wh = (l == 0) ? Wh0 : (l == 1) ? Wh1 : Wh2;
  int r = idx - base;
  int c = r >> 8, t = r & 255;
  float v[4];
#pragma unroll
  for (int i2 = 0; i2 < 4; ++i2) {
    int k = c * 4 + i2;
    v[i2] = (k < fi) ? ldi(Wx, (long)k * 256 + t, f32)
                     : ldi(Wh, (long)(k - fi) * 256 + t, f32);
  }
  float4 o; o.x = v[0]; o.y = v[1]; o.z = v[2]; o.w = v[3];
  LW[idx] = o;
  if (idx < 768) {
    int ll = idx >> 8, j = idx & 255;
    const void* bx = (ll == 0) ? bx0 : (ll == 1) ? bx1 : bx2;
    const void* bh = (ll == 0) ? bh0 : (ll == 1) ? bh1 : bh2;
    bsum[idx] = ldi(bx, j, f32) + ldi(bh, j, f32);
  }
}

// ---------- node projection: h = relu(nf @ Wp + bp) ----------
__global__ __launch_bounds__(256) void nodeproj_kernel(
    const int* __restrict__ dflag,
    const void* __restrict__ nf, const void* __restrict__ Wp,
    const void* __restrict__ bp, float* __restrict__ hstate) {
  bool f32 = dflag[0] != 0;
  int lane = threadIdx.x & 63;
  int n = blockIdx.x * 4 + (threadIdx.x >> 6);
  float acc = ldi(bp, lane, f32);
  for (int k = 0; k < 74; ++k)
    acc += ldi(nf, (long)n * 74 + k, f32) * ldi(Wp, k * 64 + lane, f32);
  hstate[n * 64 + lane] = fmaxf(acc, 0.0f);
}

// ---------- We2T: fp16 Bt tiles, per-k: [k 128][o 64][g' 8][j 8] ----------
// g' = g ^ (o&7), d = g*8 + j; value = We2[k][d*64 + o]
__global__ __launch_bounds__(256) void we2t_kernel(
    const int* __restrict__ dflag,
    const void* __restrict__ We2, unsigned short* __restrict__ We2T) {
  bool f32 = dflag[0] != 0;
  int idx = blockIdx.x * 256 + threadIdx.x;  // grid 2048 -> 524288
  int j = idx & 7;
  int gs = (idx >> 3) & 7;
  int o = (idx >> 6) & 63;
  int k = idx >> 12;                          // 0..127
  int g = gs ^ (o & 7);
  int d = g * 8 + j;
  We2T[idx] = f2h(ldi(We2, (long)k * 4096 + d * 64 + o, f32));
}

// ---------- be2T: fp16 Bt for hbe GEMM: [o 64][g' 8][j 8], g' = g^(o&7) ----
__global__ __launch_bounds__(256) void be2t_kernel(
    const int* __restrict__ dflag,
    const void* __restrict__ be2, unsigned short* __restrict__ be2T) {
  bool f32 = dflag[0] != 0;
  int idx = blockIdx.x * 256 + threadIdx.x;  // grid 16 -> 4096
  int j = idx & 7;
  int gs = (idx >> 3) & 7;
  int o = idx >> 6;
  int g = gs ^ (o & 7);
  int d = g * 8 + j;
  be2T[idx] = f2h(ldi(be2, (long)d * 64 + o, f32));
}

// ---------- CSR build (once per launch; dst is launch-invariant) ----------
__global__ __launch_bounds__(256) void count_kernel(
    const int* __restrict__ dst, int* __restrict__ cnt) {
  int e = blockIdx.x * 256 + threadIdx.x;
  if (e < NEDGES) atomicAdd(&cnt[dst[e]], 1);
}

__global__ __launch_bounds__(256) void scan_kernel(
    const int* __restrict__ cnt, int* __restrict__ row_ptr, int* __restrict__ cur) {
  __shared__ int part[256];
  int t = threadIdx.x;
  int base = t * 125;              // 256*125 = 32000
  int s = 0;
  for (int i = 0; i < 125; ++i) s += cnt[base + i];
  part[t] = s;
  __syncthreads();
  if (t == 0) {
    int run = 0;
    for (int i = 0; i < 256; ++i) { int v = part[i]; part[i] = run; run += v; }
  }
  __syncthreads();
  int run = part[t];
  for (int i = 0; i < 125; ++i) {
    row_ptr[base + i] = run;
    cur[base + i] = run;
    run += cnt[base + i];
  }
  if (t == 255) row_ptr[32000] = run;
}

__global__ __launch_bounds__(256) void fill_kernel(
    const int* __restrict__ dst, int* __restrict__ cur, int* __restrict__ eidx) {
  int e = blockIdx.x * 256 + threadIdx.x;
  if (e < NEDGES) { int p = atomicAdd(&cur[dst[e]], 1); eidx[p] = e; }
}

// ---------- message passing, nodes-first (Z), v3: fp16-pair edge pass ----------
// Per 2-k chunk: Z[k0/k1][o][n] via hi/lo MFMA (f32-equiv), then packed to
// fp16 pairs (one dword per (n,o)). Edge pass: msg[o] += dot2(u01, Z01[o])
// via v_dot2_f32_f16 -> half the LDS reads and ~2.4x less VALU per k vs v2,
// and half the barriers (64/tile). h fragments built from global (no h LDS).
// LDS 74.2 KB -> 2 blocks/CU.
__global__ __launch_bounds__(256, 2) void msg_z_kernel(
    const int* __restrict__ dflag,
    const float* __restrict__ hstate,
    const void* __restrict__ ef, const void* __restrict__ We1,
    const void* __restrict__ be1,
    const unsigned short* __restrict__ We2T,
    const unsigned short* __restrict__ be2T,
    const int* __restrict__ src, const int* __restrict__ eidx,
    const int* __restrict__ row_ptr,
    float* __restrict__ msgbuf) {
  bool f32 = dflag[0] != 0;
  __shared__ __align__(16) unsigned short BtL[2][8192];  // 32768 B (dbuf, 2 k)
  __shared__ __align__(16) unsigned int Zs[2][64][68];   // 34816 B (dbuf, pad 17q)
  __shared__ float we1T_s[1536];                         //  6144 B [k][j]
  __shared__ float be1_s[128];                           //   512 B
  // total 74240 B -> 2 blocks/CU

  int t = threadIdx.x, lane = t & 63, w = t >> 6;
  int c16 = lane & 15, q = lane >> 4;
  int nb = blockIdx.x * 64;                              // 500 blocks
  int p0 = row_ptr[nb], p1 = row_ptr[nb + 64];
  int nE = p1 - p0;
  if (nE <= 0) return;

  // ---- stage we1 transposed, be1 ----
  for (int i = t; i < 1536; i += 256) {
    int k = i / 12, j = i - k * 12;
    we1T_s[i] = ldi(We1, j * 128 + k, f32);              // We1 is [12][128]
  }
  if (t < 128) be1_s[t] = ldi(be1, t, f32);

  // ---- h fragments (B-operand, hi/lo fp16) straight from global ----
  HFrag bhi[4][2], blo[4][2];
#pragma unroll
  for (int nt = 0; nt < 4; ++nt)
#pragma unroll
    for (int ks = 0; ks < 2; ++ks) {
      const float* hp = hstate + (size_t)(nb + nt * 16 + c16) * 64 + ks * 32 + q * 8;
      float4 v0 = *(const float4*)hp;
      float4 v1 = *(const float4*)(hp + 4);
      float vv[8] = {v0.x, v0.y, v0.z, v0.w, v1.x, v1.y, v1.z, v1.w};
#pragma unroll
      for (int j = 0; j < 8; ++j) {
        HS hi; hi.h = (_Float16)vv[j];
        bhi[nt][ks].s[j] = hi.u;
        blo[nt][ks].s[j] = f2h(vv[j] - (float)hi.h);
      }
    }
  __syncthreads();                       // we1T/be1 staged

  int arow = (w * 16 + c16) * 64;        // A-frag row base (shorts) per k-block
  int g0q = (q ^ (c16 & 7)) * 8;         // d-half 0 granule offset
  int g1q = ((4 + q) ^ (c16 & 7)) * 8;   // d-half 1 granule offset

  // ---- edge tiles of 256 (virtually always a single tile) ----
  for (int et = 0; et < nE; et += 256) {
    if (et > 0) SAFE_BARRIER();          // prev tile's Zs readers done
    int me = et + t;
    bool act = me < nE;
    int pos = p0 + (act ? me : 0);
    int eg = eidx[pos];
    int r = src[eg] - nb;                // 0..63 (in-graph edges)
    float efr[12];
#pragma unroll
    for (int j = 0; j < 12; ++j) efr[j] = ldi(ef, (long)eg * 12 + j, f32);

    // ---- DMA beT -> BtL[0] (2), chunk0 (k0,k1) -> BtL[1] (4) ----
    dma16(&BtL[0][0] + w * 1024, be2T + w * 1024 + lane * 8);
    dma16(&BtL[0][0] + w * 1024 + 512, be2T + w * 1024 + 512 + lane * 8);
    dma16(&BtL[1][0] + w * 1024, We2T + w * 1024 + lane * 8);
    dma16(&BtL[1][0] + w * 1024 + 512, We2T + w * 1024 + 512 + lane * 8);
    dma16(&BtL[1][0] + 4096 + w * 1024, We2T + 4096 + w * 1024 + lane * 8);
    dma16(&BtL[1][0] + 4096 + w * 1024 + 512, We2T + 4096 + w * 1024 + 512 + lane * 8);
    WAIT_VM0();                          // edge regs + beT + chunk0 ready

    // ---- hbe[o][n] = sum_d be2T[o][d] * h[n][d]  (f32) ----
    floatx4 hacc[4];
#pragma unroll
    for (int nt = 0; nt < 4; ++nt) hacc[nt] = (floatx4){0.f, 0.f, 0.f, 0.f};
    {
      HFrag aB0, aB1;
      aB0.u4 = *(const uint4*)&BtL[0][arow + g0q];
      aB1.u4 = *(const uint4*)&BtL[0][arow + g1q];
#pragma unroll
      for (int nt = 0; nt < 4; ++nt) {
        hacc[nt] = MFMA_F16(aB0.v, bhi[nt][0].v, hacc[nt], 0, 0, 0);
        hacc[nt] = MFMA_F16(aB0.v, blo[nt][0].v, hacc[nt], 0, 0, 0);
        hacc[nt] = MFMA_F16(aB1.v, bhi[nt][1].v, hacc[nt], 0, 0, 0);
        hacc[nt] = MFMA_F16(aB1.v, blo[nt][1].v, hacc[nt], 0, 0, 0);
      }
    }
    __builtin_amdgcn_sched_barrier(0);
    WAIT_LGKM0();                        // beT frag reads done
    __builtin_amdgcn_sched_barrier(0);
    // chunk1 -> BtL[0] (overwrites beT; wave-private rows, reads drained)
    dma16(&BtL[0][0] + w * 1024, We2T + 8192 + w * 1024 + lane * 8);
    dma16(&BtL[0][0] + w * 1024 + 512, We2T + 8192 + w * 1024 + 512 + lane * 8);
    dma16(&BtL[0][0] + 4096 + w * 1024, We2T + 12288 + w * 1024 + lane * 8);
    dma16(&BtL[0][0] + 4096 + w * 1024 + 512, We2T + 12288 + w * 1024 + 512 + lane * 8);
    // store hbe (f32) -> Zs[1] as [n][o]
#pragma unroll
    for (int nt = 0; nt < 4; ++nt)
      *(floatx4*)&Zs[1][nt * 16 + c16][w * 16 + q * 4] = hacc[nt];
    SAFE_BARRIER();                      // Zs[1] (hbe) visible

    // ---- msg init from hbe ----
    floatx4 msgv[16];
    if (act) {
#pragma unroll
      for (int og = 0; og < 16; ++og)
        msgv[og] = *(const floatx4*)&Zs[1][r][og * 4];
    }

    // ---- chunk loop: 64 chunks x 2 k  (EH = 128) ----
    for (int c = 0; c < 64; ++c) {
      int cb = (c + 1) & 1;              // chunk c lives in BtL[cb]
      int zc = c & 1;                    // Z dbuf index
      if (c == 63) WAIT_VM0(); else WAIT_VM4();
      HFrag a00, a01, a10, a11;          // (k0|k1) x (d-half 0|1)
      a00.u4 = *(const uint4*)&BtL[cb][arow + g0q];
      a01.u4 = *(const uint4*)&BtL[cb][arow + g1q];
      a10.u4 = *(const uint4*)&BtL[cb][4096 + arow + g0q];
      a11.u4 = *(const uint4*)&BtL[cb][4096 + arow + g1q];
      __builtin_amdgcn_sched_barrier(0);
      WAIT_LGKM0();                      // frags in regs before buffer reuse
      __builtin_amdgcn_sched_barrier(0);
      if (c + 2 < 64) {                  // prefetch chunk c+2 into freed buffer
        const unsigned short* G = We2T + (size_t)(c + 2) * 8192 + w * 1024 + lane * 8;
        unsigned short* L = &BtL[cb][0] + w * 1024;
        dma16(L, G); dma16(L + 512, G + 512);
        dma16(L + 4096, G + 4096); dma16(L + 4096 + 512, G + 4096 + 512);
      }
      floatx4 z0[4], z1[4];
#pragma unroll
      for (int nt = 0; nt < 4; ++nt) {
        z0[nt] = (floatx4){0.f, 0.f, 0.f, 0.f};
        z1[nt] = (floatx4){0.f, 0.f, 0.f, 0.f};
      }
#pragma unroll
      for (int nt = 0; nt < 4; ++nt) {
        z0[nt] = MFMA_F16(a00.v, bhi[nt][0].v, z0[nt], 0, 0, 0);
        z0[nt] = MFMA_F16(a00.v, blo[nt][0].v, z0[nt], 0, 0, 0);
        z0[nt] = MFMA_F16(a01.v, bhi[nt][1].v, z0[nt], 0, 0, 0);
        z0[nt] = MFMA_F16(a01.v, blo[nt][1].v, z0[nt], 0, 0, 0);
        z1[nt] = MFMA_F16(a10.v, bhi[nt][0].v, z1[nt], 0, 0, 0);
        z1[nt] = MFMA_F16(a10.v, blo[nt][0].v, z1[nt], 0, 0, 0);
        z1[nt] = MFMA_F16(a11.v, bhi[nt][1].v, z1[nt], 0, 0, 0);
        z1[nt] = MFMA_F16(a11.v, blo[nt][1].v, z1[nt], 0, 0, 0);
      }
      // pack (k0,k1) fp16 pairs and store
#pragma unroll
      for (int nt = 0; nt < 4; ++nt) {
        uint4 st;
        HS p0h, p1h;
        p0h.h = (_Float16)z0[nt][0]; p1h.h = (_Float16)z1[nt][0];
        st.x = (unsigned int)p0h.u | ((unsigned int)p1h.u << 16);
        p0h.h = (_Float16)z0[nt][1]; p1h.h = (_Float16)z1[nt][1];
        st.y = (unsigned int)p0h.u | ((unsigned int)p1h.u << 16);
        p0h.h = (_Float16)z0[nt][2]; p1h.h = (_Float16)z1[nt][2];
        st.z = (unsigned int)p0h.u | ((unsigned int)p1h.u << 16);
        p0h.h = (_Float16)z0[nt][3]; p1h.h = (_Float16)z1[nt][3];
        st.w = (unsigned int)p0h.u | ((unsigned int)p1h.u << 16);
        *(uint4*)&Zs[zc][nt * 16 + c16][w * 16 + q * 4] = st;
      }
      SAFE_BARRIER();                    // Z(c) visible; prev buf readers done

      // edge pass: u pair (fp16) . Z pairs via v_dot2_f32_f16
      if (act) {
        int k0 = c * 2;
        float u0 = be1_s[k0], u1 = be1_s[k0 + 1];
#pragma unroll
        for (int j = 0; j < 12; ++j) {
          u0 += efr[j] * we1T_s[k0 * 12 + j];
          u1 += efr[j] * we1T_s[(k0 + 1) * 12 + j];
        }
        u0 = fmaxf(u0, 0.f); u1 = fmaxf(u1, 0.f);
        HS ua, ub; ua.h = (_Float16)u0; ub.h = (_Float16)u1;
        UH2 uu; uu.u = (unsigned int)ua.u | ((unsigned int)ub.u << 16);
#pragma unroll
        for (int og = 0; og < 16; ++og) {
          uint4 zz = *(const uint4*)&Zs[zc][r][og * 4];
          UH2 a;
          a.u = zz.x; msgv[og][0] = __builtin_amdgcn_fdot2(a.h, uu.h, msgv[og][0], false);
          a.u = zz.y; msgv[og][1] = __builtin_amdgcn_fdot2(a.h, uu.h, msgv[og][1], false);
          a.u = zz.z; msgv[og][2] = __builtin_amdgcn_fdot2(a.h, uu.h, msgv[og][2], false);
          a.u = zz.w; msgv[og][3] = __builtin_amdgcn_fdot2(a.h, uu.h, msgv[og][3], false);
        }
      }
    }

    // ---- store msg (CSR position order, same contract as before) ----
    if (act) {
      float* mp = msgbuf + (size_t)pos * 64;
#pragma unroll
      for (int og = 0; og < 16; ++og) *(floatx4*)(mp + og * 4) = msgv[og];
    }
  }
}

// ---------- GRU step: MFMA gates (fp16, X hi/lo split) + fused CSR gather ------
__global__ __launch_bounds__(256, 2) void gru_kernel(
    float* __restrict__ hstate, const float* __restrict__ msgbuf,
    const int* __restrict__ row_ptr,
    const unsigned short* __restrict__ WxH, const unsigned short* __restrict__ WhH,
    const float* __restrict__ bxf, const float* __restrict__ bhf,
    const float* __restrict__ bconvf) {
  __shared__ __align__(16) unsigned short Xhi[64][72];   // 9216 B
  __shared__ __align__(16) unsigned short Xlo[64][72];   // 9216 B
  __shared__ __align__(16) unsigned short Hh[64][72];    // 9216 B
  __shared__ unsigned short SRZ[128][68];                // 17408 B (fp16 sig(r/z))
  __shared__ float GXn[64][66];                          // 16896 B
  __shared__ float GHn[64][66];                          // 16896 B
  int t = threadIdx.x;
  int nb = blockIdx.x * 64;                              // 500 blocks

#pragma unroll
  for (int i = 0; i < 16; ++i) {
    int idx = t + i * 256;
    int n = idx >> 6, c = idx & 63;
    int node = nb + n;
    float a = bconvf[c];
    int p0 = row_ptr[node], p1 = row_ptr[node + 1];
    for (int p = p0; p < p1; ++p) a += msgbuf[(size_t)p * 64 + c];
    a = fmaxf(a, 0.f);
    HS hi; hi.h = (_Float16)a;
    Xhi[n][c] = hi.u;
    Xlo[n][c] = f2h(a - (float)hi.h);
    Hh[n][c] = f2h(hstate[(size_t)node * 64 + c]);
  }
  __syncthreads();

  int lane = t & 63, w = t >> 6;
  int c16 = lane & 15, q = lane >> 4;
  floatx4 gx[3][4], gh[3][4];
#pragma unroll
  for (int jt = 0; jt < 3; ++jt)
#pragma unroll
    for (int nt = 0; nt < 4; ++nt) {
      gx[jt][nt] = (floatx4){0.f, 0.f, 0.f, 0.f};
      gh[jt][nt] = (floatx4){0.f, 0.f, 0.f, 0.f};
    }
#pragma unroll
  for (int kc = 0; kc < 2; ++kc) {
    int kof = kc * 32 + q * 8;
    HFrag ax[3], ah[3];
#pragma unroll
    for (int jt = 0; jt < 3; ++jt) {
      long off = (long)((w * 3 + jt) * 16 + c16) * 64 + kof;
      ax[jt].u4 = *(const uint4*)(WxH + off);
      ah[jt].u4 = *(const uint4*)(WhH + off);
    }
    HFrag bxh[4], bxl[4], bhf_[4];
#pragma unroll
    for (int nt = 0; nt < 4; ++nt) {
      int n = nt * 16 + c16;
      bxh[nt].u4 = *(const uint4*)&Xhi[n][kof];
      bxl[nt].u4 = *(const uint4*)&Xlo[n][kof];
      bhf_[nt].u4 = *(const uint4*)&Hh[n][kof];
    }
#pragma unroll
    for (int jt = 0; jt < 3; ++jt)
#pragma unroll
      for (int nt = 0; nt < 4; ++nt) {
        gx[jt][nt] = MFMA_F16(ax[jt].v, bxh[nt].v, gx[jt][nt], 0, 0, 0);
        gx[jt][nt] = MFMA_F16(ax[jt].v, bxl[nt].v, gx[jt][nt], 0, 0, 0);
        gh[jt][nt] = MFMA_F16(ah[jt].v, bhf_[nt].v, gh[jt][nt], 0, 0, 0);
      }
  }

#pragma unroll
  for (int jt = 0; jt < 3; ++jt) {
#pragma unroll
    for (int rr = 0; rr < 4; ++rr) {
      int j = (w * 3 + jt) * 16 + q * 4 + rr;
      float bxv = bxf[j], bhv = bhf[j];
#pragma unroll
      for (int nt = 0; nt < 4; ++nt) {
        int n = nt * 16 + c16;
        float vx = gx[jt][nt][rr] + bxv;
        float vh = gh[jt][nt][rr] + bhv;
        if (j < 128) {
          SRZ[j][n] = f2h(sigmf(vx + vh));
        } else {
          GXn[j - 128][n] = vx;
          GHn[j - 128][n] = vh;
        }
      }
    }
  }
  __syncthreads();

#pragma unroll
  for (int i = 0; i < 16; ++i) {
    int idx = t + i * 256;
    int n = idx >> 6, f = idx & 63;
    float r = h2f(SRZ[f][n]);
    float z = h2f(SRZ[64 + f][n]);
    float ng = tanhf(GXn[f][n] + r * GHn[f][n]);
    size_t gi = (size_t)(nb + n) * 64 + f;
    float ho = hstate[gi];
    hstate[gi] = (1.0f - z) * ng + z * ho;
  }
}

// ---------- Set2Set fused x6 + head ----------
__global__ __launch_bounds__(512) void s2s6_kernel(
    const int* __restrict__ dflag,
    const float* __restrict__ hstate,
    const float4* __restrict__ LW,        // [l0:48|l1:32|l2:32] x 256 float4
    const float* __restrict__ lstm_bsum,  // [3][256] bx+bh
    const void* __restrict__ Wout1, const void* __restrict__ bout1,
    const void* __restrict__ Wout2, const void* __restrict__ bout2,
    float* __restrict__ out) {
  bool f32 = dflag[0] != 0;
  __shared__ float xq[4][128];        // q_star per graph
  __shared__ float inb[4][192];       // combined [xq(fi) | h(64)] per graph
  __shared__ float gates[4][256];
  __shared__ float al[4][32];
  __shared__ float hsvf[768];         // 3 layers x 4 graphs x 64
  __shared__ float csvf[768];
  int g0 = blockIdx.x * 4;
  int t = threadIdx.x;

  for (int i = t; i < 512; i += 512) xq[i >> 7][i & 127] = 0.f;
  for (int i = t; i < 768; i += 512) { hsvf[i] = 0.f; csvf[i] = 0.f; }
  __syncthreads();

  int tt = t & 255, gp = t >> 8;      // gate id, graph-pair
  int ga = gp * 2, gb = ga + 1;

  for (int s = 0; s < 6; ++s) {
#pragma unroll
    for (int l = 0; l < 3; ++l) {
      const int fi = (l == 0) ? 128 : 64;
      const int tot = fi + 64;
      for (int i = t; i < 4 * tot; i += 512) {
        int g = i / tot, k = i - g * tot;
        inb[g][k] = (k < fi) ? xq[g][k] : hsvf[l * 256 + g * 64 + (k - fi)];
      }
      __syncthreads();
      const int nch = tot >> 2;
      const float4* wrow = LW + ((l == 0) ? 0 : (l == 1) ? 12288 : 20480) + tt;
      float bs = lstm_bsum[l * 256 + tt];
      float a0 = bs, a1 = bs;
#pragma unroll 8
      for (int cch = 0; cch < nch; ++cch) {
        float4 wv = wrow[(size_t)cch * 256];
        float4 x0 = *(const float4*)&inb[ga][cch * 4];
        float4 x1 = *(const float4*)&inb[gb][cch * 4];
        a0 += wv.x * x0.x + wv.y * x0.y + wv.z * x0.z + wv.w * x0.w;
        a1 += wv.x * x1.x + wv.y * x1.y + wv.z * x1.z + wv.w * x1.w;
      }
      gates[ga][tt] = a0;
      gates[gb][tt] = a1;
      __syncthreads();
      if (t < 256) {
        int gg = t >> 6, u = t & 63;
        float ig = sigmf(gates[gg][u]);
        float fg = sigmf(gates[gg][64 + u]);
        float gv = tanhf(gates[gg][128 + u]);
        float og = sigmf(gates[gg][192 + u]);
        int ci = l * 256 + t;
        float cc = fg * csvf[ci] + ig * gv;
        float hn = og * tanhf(cc);
        csvf[ci] = cc;
        hsvf[ci] = hn;
        xq[gg][u] = hn;
      }
      __syncthreads();
    }
    if (t < 256) {
      int gg = t >> 6, tl = t & 63;
      int g = g0 + gg;
      int n = tl & 31, half = tl >> 5;
      const float* hrow = hstate + (size_t)(g * 32 + n) * 64 + half * 32;
      const float* qp = &xq[gg][half * 32];
      float p = 0.f;
#pragma unroll
      for (int k = 0; k < 32; ++k) p += hrow[k] * qp[k];
      p += __shfl_xor(p, 32, 64);
      if (half == 0) {
        float m = p;
#pragma unroll
        for (int s2 = 1; s2 < 32; s2 <<= 1) m = fmaxf(m, __shfl_xor(m, s2, 32));
        float e = expf(p - m);
        float sum = e;
#pragma unroll
        for (int s2 = 1; s2 < 32; s2 <<= 1) sum += __shfl_xor(sum, s2, 32);
        al[gg][n] = e / sum;
      }
      float acc = 0.f;
#pragma unroll 8
      for (int nn = 0; nn < 32; ++nn)
        acc += al[gg][nn] * hstate[(size_t)(g * 32 + nn) * 64 + tl];
      xq[gg][64 + tl] = acc;
    }
    __syncthreads();
  }

  if (t < 256) {
    int gg = t >> 6, tl = t & 63;
    int g = g0 + gg;
    float acc = ldi(bout1, tl, f32);
#pragma unroll 16
    for (int k = 0; k < 128; ++k) acc += xq[gg][k] * ldi(Wout1, k * 64 + tl, f32);
    acc = fmaxf(acc, 0.0f);
    float p = acc * ldi(Wout2, tl, f32);
#pragma unroll
    for (int m = 1; m < 64; m <<= 1) p += __shfl_xor(p, m, 64);
    if (tl == 0) out[g] = p + ldi(bout2, 0, f32);
    out[1000 + g * 128 + tl] = xq[gg][tl];
    out[1000 + g * 128 + 64 + tl] = xq[gg][64 + tl];
  }
}

// ---------- launch ----------
extern "C" void kernel_launch(void* const* d_in, const int* in_sizes, int n_in,
                              void* d_out, int out_size, void* d_ws, size_t ws_size,
                              hipStream_t stream) {
  (void)in_sizes; (void)n_in; (void)out_size; (void)ws_size;
  const void* node_feats = d_in[0];
  const void* edge_feats = d_in[1];
  const int* src = (const int*)d_in[2];
  const int* dst = (const int*)d_in[3];
  const void* Wp = d_in[5];
  const void* bp = d_in[6];
  const void* We1 = d_in[7];
  const void* be1 = d_in[8];
  const void* We2 = d_in[9];
  const void* be2 = d_in[10];
  const void* b_conv = d_in[11];
  const void* gWx = d_in[12];
  const void* gWh = d_in[13];
  const void* gbx = d_in[14];
  const void* gbh = d_in[15];
  const void* Wout1 = d_in[16];
  const void* bout1 = d_in[17];
  const void* Wout2 = d_in[18];
  const void* bout2 = d_in[19];

  // workspace layout (~31.9 MB; proven-mapped region >= 44.5 MB)
  int* dflag = (int*)d_ws;                                    // 64 ints reserved
  float* hstate = (float*)d_ws + 64;                          // 32000*64 f32
  float* msgbuf = hstate + NNODES * 64;                       // 80000*64 f32
  unsigned short* We2T = (unsigned short*)(msgbuf + (size_t)NEDGES * 64); // 524288 fp16
  unsigned short* WxH = We2T + 524288;                        // 12288 fp16
  unsigned short* WhH = WxH + 12288;                          // 12288 fp16
  float* bxf = (float*)(WhH + 12288);                         // 192
  float* bhf = bxf + 192;                                     // 192
  float* bconvf = bhf + 192;                                  // 64
  int* row_ptr = (int*)(bconvf + 64);                         // 32001
  int* cur = row_ptr + 32001;                                 // 32000
  int* cnt = cur + 32000;                                     // 32000
  int* eidx = cnt + 32000;                                    // 80000
  uintptr_t lwp = (uintptr_t)(eidx + 80000);
  lwp = (lwp + 15) & ~(uintptr_t)15;                          // 16B align
  float4* LWf = (float4*)lwp;                                 // 28672 float4 (448 KB)
  float* lstm_bsum = (float*)(LWf + 28672);                   // 768 f32
  unsigned short* be2T = (unsigned short*)(lstm_bsum + 768);  // 4096 fp16

  (void)hipMemsetAsync(cnt, 0, (size_t)NNODES * sizeof(int), stream);

  detect_kernel<<<1, 256, 0, stream>>>((const unsigned short*)node_feats, dflag);
  prep_kernel<<<48, 256, 0, stream>>>(dflag, gWx, gWh, gbx, gbh, b_conv,
                                      WxH, WhH, bxf, bhf, bconvf);
  nodeproj_kernel<<<NNODES / 4, 256, 0, stream>>>(dflag, node_feats, Wp, bp, hstate);
  we2t_kernel<<<2048, 256, 0, stream>>>(dflag, We2, We2T);
  be2t_kernel<<<16, 256, 0, stream>>>(dflag, be2, be2T);
  lstmprep_kernel<<<112, 256, 0, stream>>>(dflag,
      d_in[20], d_in[21], d_in[22], d_in[23],
      d_in[24], d_in[25], d_in[26], d_in[27],
      d_in[28], d_in[29], d_in[30], d_in[31],
      LWf, lstm_bsum);

  count_kernel<<<(NEDGES + 255) / 256, 256, 0, stream>>>(dst, cnt);
  scan_kernel<<<1, 256, 0, stream>>>(cnt, row_ptr, cur);
  fill_kernel<<<(NEDGES + 255) / 256, 256, 0, stream>>>(dst, cur, eidx);

  for (int step = 0; step < 6; ++step) {
    msg_z_kernel<<<NNODES / 64, 256, 0, stream>>>(
        dflag, hstate, edge_feats, We1, be1, We2T, be2T, src, eidx, row_ptr,
        msgbuf);
    gru_kernel<<<NNODES / 64, 256, 0, stream>>>(hstate, msgbuf, row_ptr,
                                                WxH, WhH, bxf, bhf, bconvf);
  }
  s2s6_kernel<<<NGRAPH / 4, 512, 0, stream>>>(dflag, hstate,
      (const float4*)LWf, lstm_bsum,
      Wout1, bout1, Wout2, bout2, (float*)d_out);
}